// Round 4
// baseline (1268.851 us; speedup 1.0000x reference)
//
#include <hip/hip_runtime.h>
#include <hip/hip_bf16.h>

typedef unsigned int u32;
typedef unsigned short u16;
typedef unsigned long long u64;
typedef __attribute__((ext_vector_type(8))) short short8;
typedef __attribute__((ext_vector_type(4))) float f32x4;

__device__ __forceinline__ u32 f2bf(float f){
  u32 u = __float_as_uint(f);
  return (u + 0x7fffu + ((u >> 16) & 1u)) >> 16;   // RNE to bf16
}
__device__ __forceinline__ float bflo(u32 p){ return __uint_as_float(p << 16); }
__device__ __forceinline__ float bfhi(u32 p){ return __uint_as_float(p & 0xffff0000u); }

// ---------------- Kernel A: dense projections, packed bf16 output ----------
// out[node*64+c] = pack(x@wA [c], x@wB [c])   (lo = primary, hi = cci)
__global__ __launch_bounds__(256) void proj_kernel(
    const float* __restrict__ xs, const float* __restrict__ xt,
    const float* __restrict__ w_s, const float* __restrict__ w_t,
    const float* __restrict__ w_s_cci, const float* __restrict__ w_t_cci,
    u32* __restrict__ mS, u32* __restrict__ mT, int ns, int nt)
{
  __shared__ float wa[4096], wb[4096];
  const int dir = blockIdx.y;
  const float* x  = dir ? xt : xs;
  const float* wA = dir ? w_t : w_s;
  const float* wB = dir ? w_t_cci : w_s_cci;
  u32* out = dir ? mT : mS;
  const int n = dir ? nt : ns;
  const int tid = threadIdx.x;
  for (int i = tid; i < 4096; i += 256){ wa[i] = wA[i]; wb[i] = wB[i]; }
  __syncthreads();
  const int wid = tid >> 6, lane = tid & 63;
  for (int row = blockIdx.x*4 + wid; row < n; row += gridDim.x*4){
    float xv = x[(size_t)row*64 + lane];
    float accA = 0.f, accB = 0.f;
    #pragma unroll
    for (int k = 0; k < 64; k++){
      float xk = __shfl(xv, k, 64);
      accA = fmaf(xk, wa[k*64 + lane], accA);
      accB = fmaf(xk, wb[k*64 + lane], accB);
    }
    out[(size_t)row*64 + lane] = f2bf(accA) | (f2bf(accB) << 16);
  }
}

// ---------------- Kernel A2: transpose+cast linear weights -----------------
// Wt[col][k] = bf16(W[k][col]);  W flat [576][64]
__global__ __launch_bounds__(256) void wprep_kernel(
  const float* __restrict__ srcW, const float* __restrict__ tgtW,
  u16* __restrict__ WtS, u16* __restrict__ WtT)
{
  int idx = blockIdx.x*256 + threadIdx.x;
  if (idx < 576*64){
    int col = idx / 576, k = idx - col*576;
    WtS[idx] = (u16)f2bf(srcW[(size_t)k*64 + col]);
    WtT[idx] = (u16)f2bf(tgtW[(size_t)k*64 + col]);
  }
}

// ---------------- Kernel B: histogram ----------------
__global__ __launch_bounds__(256) void hist_kernel(
  const int* __restrict__ rows, const int* __restrict__ cols,
  int* cntR, int* cntC, int E)
{
  int e = blockIdx.x*256 + threadIdx.x;
  if (e < E){
    atomicAdd(&cntR[rows[e]], 1);
    atomicAdd(&cntC[cols[e]], 1);
  }
}

// ---------------- Kernel C: single-block exclusive scan (x2 blocks) --------
__global__ __launch_bounds__(1024) void scan_kernel(
  const int* __restrict__ cntC, const int* __restrict__ cntR,
  int* ptrC, int* ptrR, int* curC, int* curR, int ns, int nt)
{
  __shared__ int lds[1024];
  const int* cnt; int* ptr; int* cur; int n;
  if (blockIdx.x == 0){ cnt=cntC; ptr=ptrC; cur=curC; n=ns; }
  else                { cnt=cntR; ptr=ptrR; cur=curR; n=nt; }
  const int t = threadIdx.x;
  const int C = (n + 1023) / 1024;
  const int base = t*C;
  int s = 0;
  for (int i = 0; i < C; i++){ int idx = base+i; if (idx < n) s += cnt[idx]; }
  lds[t] = s; __syncthreads();
  for (int off = 1; off < 1024; off <<= 1){
    int v = 0; if (t >= off) v = lds[t-off];
    __syncthreads();
    lds[t] += v;
    __syncthreads();
  }
  int run = lds[t] - s;        // exclusive prefix of this chunk
  for (int i = 0; i < C; i++){
    int idx = base+i;
    if (idx < n){ ptr[idx] = run; cur[idx] = run; run += cnt[idx]; }
  }
  if (t == 1023) ptr[n] = lds[1023];
}

// ---------------- Kernel D: scatter edges into CSR (rows) + CSC (cols) -----
// (exact R2 form: 6 independent 4B streams — measured-fastest variant)
__global__ __launch_bounds__(256) void scatter_kernel(
  const int* __restrict__ rows, const int* __restrict__ cols,
  const float* __restrict__ nbv, const float* __restrict__ ccv,
  int* curR, int* curC,
  int* nbrT, float* w0T, float* w1T,
  int* nbrS, float* w0S, float* w1S, int E)
{
  int e = blockIdx.x*256 + threadIdx.x;
  if (e < E){
    int r = rows[e], c = cols[e];
    float a = nbv[e], b = ccv[e];
    int pT = atomicAdd(&curR[r], 1);
    nbrT[pT] = c; w0T[pT] = a; w1T[pT] = b;
    int pS = atomicAdd(&curC[c], 1);
    nbrS[pS] = r; w0S[pS] = a; w1S[pS] = b;
  }
}

// ---------------- Kernel E: channel-split aggregation ----------------------
// grid.z = 8 phases: dir = z>>2, slice = z&3. Per phase the gather table
// slice is 50000*64B = 3.2MB -> resident in each XCD's 4MB L2.
// Wave = 4 edge-groups x 16 channels; 1 wave per segment per phase.
// stats layout: [slice][seg][blk0..5][16ch] u16  (192B contiguous per seg)
__global__ __launch_bounds__(256) void agg_kernel(
  const int* __restrict__ ptrC, const int* __restrict__ ptrR,
  const int* __restrict__ nbrS, const float* __restrict__ w0S, const float* __restrict__ w1S,
  const int* __restrict__ nbrT, const float* __restrict__ w0T, const float* __restrict__ w1T,
  const u32* __restrict__ mS, const u32* __restrict__ mT,
  u16* __restrict__ statsS, u16* __restrict__ statsT, int ns, int nt)
{
  const int z = blockIdx.z;
  const int dir = z >> 2, slice = z & 3;
  const int nseg = dir ? nt : ns;
  const int* ptr = dir ? ptrR : ptrC;
  const int* nbr = dir ? nbrT : nbrS;
  const float* w0 = dir ? w0T : w0S;
  const float* w1 = dir ? w1T : w1S;
  const u32* mtab = dir ? mS : mT;     // msg_src gathers target features & v.v.
  u16* stats = dir ? statsT : statsS;

  const int wid = threadIdx.x >> 6, lane = threadIdx.x & 63;
  const int seg = blockIdx.x*4 + wid;
  if (seg >= nseg) return;
  const int beg = ptr[seg], end = ptr[seg+1];

  const int egrp = lane >> 4;
  const int col = slice*16 + (lane & 15);

  float s0=0.f, s1=0.f, s2=0.f;
  float mx0=-INFINITY, mx1=-INFINITY, mx2=-INFINITY;

  // rotated-register software pipeline: edge record for e prefetched
  int e = beg + egrp;
  bool v = e < end;
  int nb = 0; float a = 0.f, b = 0.f;
  if (v){
    nb = __builtin_nontemporal_load(&nbr[e]);
    a  = __builtin_nontemporal_load(&w0[e]);
    b  = __builtin_nontemporal_load(&w1[e]);
  }
  while (__any(v)){
    int e2 = e + 4;
    bool v2 = e2 < end;
    int nb2 = 0; float a2 = 0.f, b2 = 0.f;
    if (v2){
      nb2 = __builtin_nontemporal_load(&nbr[e2]);
      a2  = __builtin_nontemporal_load(&w0[e2]);
      b2  = __builtin_nontemporal_load(&w1[e2]);
    }
    if (v){
      u32 f = mtab[(size_t)nb*64 + col];     // 16 lanes -> one 64B line (L2-hot)
      float g0 = bflo(f) * a;
      float g1 = bfhi(f) * b;
      float g2 = g1 * a;
      s0 += g0; s1 += g1; s2 += g2;
      mx0 = fmaxf(mx0, g0); mx1 = fmaxf(mx1, g1); mx2 = fmaxf(mx2, g2);
    }
    v = v2; e = e2; nb = nb2; a = a2; b = b2;
  }

  // reduce across the 4 edge-groups (lane bits 4,5)
  #pragma unroll
  for (int d = 16; d <= 32; d <<= 1){
    s0 += __shfl_xor(s0, d, 64);
    s1 += __shfl_xor(s1, d, 64);
    s2 += __shfl_xor(s2, d, 64);
    mx0 = fmaxf(mx0, __shfl_xor(mx0, d, 64));
    mx1 = fmaxf(mx1, __shfl_xor(mx1, d, 64));
    mx2 = fmaxf(mx2, __shfl_xor(mx2, d, 64));
  }
  if (end == beg){ mx0 = 0.f; mx1 = 0.f; mx2 = 0.f; }  // empty segment -> 0

  if (lane < 16){
    size_t base = ((size_t)slice*nseg + seg)*96 + (lane & 15);
    __builtin_nontemporal_store((u16)f2bf(s0),  &stats[base      ]);
    __builtin_nontemporal_store((u16)f2bf(s1),  &stats[base + 16 ]);
    __builtin_nontemporal_store((u16)f2bf(s2),  &stats[base + 32 ]);
    __builtin_nontemporal_store((u16)f2bf(mx0), &stats[base + 48 ]);
    __builtin_nontemporal_store((u16)f2bf(mx1), &stats[base + 64 ]);
    __builtin_nontemporal_store((u16)f2bf(mx2), &stats[base + 80 ]);
  }
}

// ---------------- Kernel F: MFMA GEMM  [64 segs x 576] @ [576 x 64] --------
// A = h (expanded stats, bf16, LDS, padded rows); B = Wt in registers.
#define HROW 584   // padded LDS row stride in u16 (584*2 B, 16B-aligned)

__global__ __launch_bounds__(256) void lin_kernel(
  const u16* __restrict__ statsS, const u16* __restrict__ statsT,
  const int* __restrict__ ptrC, const int* __restrict__ ptrR,
  const u16* __restrict__ WtS, const u16* __restrict__ WtT,
  const float* __restrict__ srcB, const float* __restrict__ tgtB,
  float* __restrict__ outp, int ns, int nt)
{
  __shared__ u16 h[64*HROW];
  __shared__ float invc[64];
  const int dir = blockIdx.y;
  const u16* stats = dir ? statsT : statsS;
  const int* ptr   = dir ? ptrR : ptrC;
  const u16* Wt    = dir ? WtT : WtS;
  const float* Bg  = dir ? tgtB : srcB;
  const int n = dir ? nt : ns;
  float* out = outp + (dir ? (size_t)ns*64 : 0);
  const int tid = threadIdx.x;
  const int wv = tid >> 6, lane = tid & 63;
  const int seg0 = blockIdx.x * 64;
  if (seg0 >= n) return;

  // B fragments: wave wv owns cols [wv*16, wv*16+16); lane holds 8 contiguous k
  const int bcol = wv*16 + (lane & 15);
  const int krow = (lane >> 4) * 8;
  short8 bfrag[18];
  #pragma unroll
  for (int t = 0; t < 18; t++)
    bfrag[t] = *(const short8*)&Wt[(size_t)bcol*576 + t*32 + krow];

  if (tid < 64){
    int seg = seg0 + tid;
    float c = (seg < n) ? (float)(ptr[seg+1] - ptr[seg]) : 1.f;
    invc[tid] = 1.f / fmaxf(c, 1.f);
  }
  __syncthreads();

  // stage stats -> h[seg][576] = [sum_p | sum_p/c | max_p] per branch p
  // stats layout: [slice][seg][blk][16] u16
  for (int idx = tid; idx < 64*192; idx += 256){
    int s = idx / 192, i = idx - s*192;
    int blk = i >> 5, cp = (i & 31) * 2;     // cp = even channel 0..62
    int seg = seg0 + s;
    u32 v = 0;
    if (seg < n)
      v = *(const u32*)&stats[((size_t)(cp >> 4)*n + seg)*96 + blk*16 + (cp & 15)];
    u32* hrow = (u32*)&h[s*HROW];
    if (blk < 3){
      hrow[(blk*192 + cp) >> 1] = v;
      float ic = invc[s];
      hrow[(blk*192 + 64 + cp) >> 1] = f2bf(bflo(v)*ic) | (f2bf(bfhi(v)*ic) << 16);
    } else {
      hrow[((blk-3)*192 + 128 + cp) >> 1] = v;
    }
  }
  __syncthreads();

  f32x4 acc[4] = {};
  const int arow = lane & 15;
  #pragma unroll
  for (int t = 0; t < 18; t++){
    #pragma unroll
    for (int rb = 0; rb < 4; rb++){
      short8 a = *(const short8*)&h[(rb*16 + arow)*HROW + t*32 + krow];
      acc[rb] = __builtin_amdgcn_mfma_f32_16x16x32_bf16(a, bfrag[t], acc[rb], 0, 0, 0);
    }
  }

  float bv = Bg[bcol] + Bg[64 + bcol] + Bg[128 + bcol];
  #pragma unroll
  for (int rb = 0; rb < 4; rb++){
    #pragma unroll
    for (int r = 0; r < 4; r++){
      int seg = seg0 + rb*16 + (lane >> 4)*4 + r;
      if (seg < n) out[(size_t)seg*64 + bcol] = acc[rb][r] + bv;
    }
  }
}

extern "C" void kernel_launch(void* const* d_in, const int* in_sizes, int n_in,
                              void* d_out, int out_size, void* d_ws, size_t ws_size,
                              hipStream_t stream)
{
  const float* xs   = (const float*)d_in[0];
  const float* xt   = (const float*)d_in[1];
  const int*   rows = (const int*)  d_in[2];
  const int*   cols = (const int*)  d_in[3];
  const float* nbv  = (const float*)d_in[4];
  const float* ccv  = (const float*)d_in[5];
  const float* w_s  = (const float*)d_in[6];
  const float* w_t  = (const float*)d_in[7];
  const float* w_sc = (const float*)d_in[8];
  const float* w_tc = (const float*)d_in[9];
  const float* srcW = (const float*)d_in[10];
  const float* srcB = (const float*)d_in[11];
  const float* tgtW = (const float*)d_in[12];
  const float* tgtB = (const float*)d_in[13];
  const int ns = in_sizes[0] / 64;
  const int nt = in_sizes[1] / 64;
  const int E  = in_sizes[4];

  char* ws = (char*)d_ws;
  size_t off = 0;
  auto alloc = [&](size_t bytes)->char* {
    char* p = ws + off;
    off = (off + bytes + 255) & ~(size_t)255;
    return p;
  };
  u32* mS    = (u32*)alloc((size_t)ns*64*4);
  u32* mT    = (u32*)alloc((size_t)nt*64*4);
  int* cntC  = (int*)alloc((size_t)(ns+nt)*4);
  int* cntR  = cntC + ns;
  int* ptrC  = (int*)alloc((size_t)(ns+1)*4);
  int* ptrR  = (int*)alloc((size_t)(nt+1)*4);
  int* curC  = (int*)alloc((size_t)ns*4);
  int* curR  = (int*)alloc((size_t)nt*4);
  int*   nbrS = (int*)  alloc((size_t)E*4);
  float* w0S  = (float*)alloc((size_t)E*4);
  float* w1S  = (float*)alloc((size_t)E*4);
  int*   nbrT = (int*)  alloc((size_t)E*4);
  float* w0T  = (float*)alloc((size_t)E*4);
  float* w1T  = (float*)alloc((size_t)E*4);
  u16* statsS = (u16*)alloc((size_t)ns*384*2);
  u16* statsT = (u16*)alloc((size_t)nt*384*2);
  u16* WtS    = (u16*)alloc((size_t)576*64*2);
  u16* WtT    = (u16*)alloc((size_t)576*64*2);

  hipMemsetAsync(cntC, 0, (size_t)(ns+nt)*4, stream);
  proj_kernel<<<dim3(128,2), 256, 0, stream>>>(xs,xt,w_s,w_t,w_sc,w_tc,mS,mT,ns,nt);
  wprep_kernel<<<(576*64 + 255)/256, 256, 0, stream>>>(srcW,tgtW,WtS,WtT);
  hist_kernel<<<(E+255)/256, 256, 0, stream>>>(rows,cols,cntR,cntC,E);
  scan_kernel<<<2, 1024, 0, stream>>>(cntC,cntR,ptrC,ptrR,curC,curR,ns,nt);
  scatter_kernel<<<(E+255)/256, 256, 0, stream>>>(rows,cols,nbv,ccv,curR,curC,
                                                  nbrT,w0T,w1T,nbrS,w0S,w1S,E);
  const int mseg = (ns > nt ? ns : nt);
  agg_kernel<<<dim3((mseg+3)/4, 1, 8), 256, 0, stream>>>(ptrC,ptrR,nbrS,w0S,w1S,
                                                         nbrT,w0T,w1T,mS,mT,
                                                         statsS,statsT,ns,nt);
  lin_kernel<<<dim3((mseg+63)/64, 2), 256, 0, stream>>>(statsS,statsT,ptrC,ptrR,
                                                        WtS,WtT,srcB,tgtB,
                                                        (float*)d_out,ns,nt);
}

// Round 5
// 1038.143 us; speedup vs baseline: 1.2222x; 1.2222x over previous
//
#include <hip/hip_runtime.h>
#include <hip/hip_bf16.h>

typedef unsigned int u32;
typedef unsigned short u16;
typedef unsigned long long u64;
typedef __attribute__((ext_vector_type(8))) short short8;
typedef __attribute__((ext_vector_type(4))) float f32x4;

__device__ __forceinline__ u32 f2bf(float f){
  u32 u = __float_as_uint(f);
  return (u + 0x7fffu + ((u >> 16) & 1u)) >> 16;   // RNE to bf16
}
__device__ __forceinline__ float bflo(u32 p){ return __uint_as_float(p << 16); }
__device__ __forceinline__ float bfhi(u32 p){ return __uint_as_float(p & 0xffff0000u); }

// ---------------- Kernel A: dense projections -> per-slice packed tables ---
// tab layout: [slice(4)][node][16ch] u32, each u32 = pack(primary, cci)
// slice table = n*64B contiguous  (3.2MB for n=50000 -> L2-resident)
__global__ __launch_bounds__(256) void proj_kernel(
    const float* __restrict__ xs, const float* __restrict__ xt,
    const float* __restrict__ w_s, const float* __restrict__ w_t,
    const float* __restrict__ w_s_cci, const float* __restrict__ w_t_cci,
    u32* __restrict__ mS, u32* __restrict__ mT, int ns, int nt)
{
  __shared__ float wa[4096], wb[4096];
  const int dir = blockIdx.y;
  const float* x  = dir ? xt : xs;
  const float* wA = dir ? w_t : w_s;
  const float* wB = dir ? w_t_cci : w_s_cci;
  u32* out = dir ? mT : mS;
  const int n = dir ? nt : ns;
  const int tid = threadIdx.x;
  for (int i = tid; i < 4096; i += 256){ wa[i] = wA[i]; wb[i] = wB[i]; }
  __syncthreads();
  const int wid = tid >> 6, lane = tid & 63;
  const int slice = lane >> 4, ch = lane & 15;
  for (int row = blockIdx.x*4 + wid; row < n; row += gridDim.x*4){
    float xv = x[(size_t)row*64 + lane];
    float accA = 0.f, accB = 0.f;
    #pragma unroll
    for (int k = 0; k < 64; k++){
      float xk = __shfl(xv, k, 64);
      accA = fmaf(xk, wa[k*64 + lane], accA);
      accB = fmaf(xk, wb[k*64 + lane], accB);
    }
    out[((size_t)slice*n + row)*16 + ch] = f2bf(accA) | (f2bf(accB) << 16);
  }
}

// ---------------- Kernel A2: transpose+cast linear weights -----------------
__global__ __launch_bounds__(256) void wprep_kernel(
  const float* __restrict__ srcW, const float* __restrict__ tgtW,
  u16* __restrict__ WtS, u16* __restrict__ WtT)
{
  int idx = blockIdx.x*256 + threadIdx.x;
  if (idx < 576*64){
    int col = idx / 576, k = idx - col*576;
    WtS[idx] = (u16)f2bf(srcW[(size_t)k*64 + col]);
    WtT[idx] = (u16)f2bf(tgtW[(size_t)k*64 + col]);
  }
}

// ---------------- Kernel B: histogram ----------------
__global__ __launch_bounds__(256) void hist_kernel(
  const int* __restrict__ rows, const int* __restrict__ cols,
  int* cntR, int* cntC, int E)
{
  int e = blockIdx.x*256 + threadIdx.x;
  if (e < E){
    atomicAdd(&cntR[rows[e]], 1);
    atomicAdd(&cntC[cols[e]], 1);
  }
}

// ---------------- Kernel C: single-block exclusive scan (x2 blocks) --------
__global__ __launch_bounds__(1024) void scan_kernel(
  const int* __restrict__ cntC, const int* __restrict__ cntR,
  int* ptrC, int* ptrR, int* curC, int* curR, int ns, int nt)
{
  __shared__ int lds[1024];
  const int* cnt; int* ptr; int* cur; int n;
  if (blockIdx.x == 0){ cnt=cntC; ptr=ptrC; cur=curC; n=ns; }
  else                { cnt=cntR; ptr=ptrR; cur=curR; n=nt; }
  const int t = threadIdx.x;
  const int C = (n + 1023) / 1024;
  const int base = t*C;
  int s = 0;
  for (int i = 0; i < C; i++){ int idx = base+i; if (idx < n) s += cnt[idx]; }
  lds[t] = s; __syncthreads();
  for (int off = 1; off < 1024; off <<= 1){
    int v = 0; if (t >= off) v = lds[t-off];
    __syncthreads();
    lds[t] += v;
    __syncthreads();
  }
  int run = lds[t] - s;
  for (int i = 0; i < C; i++){
    int idx = base+i;
    if (idx < n){ ptr[idx] = run; cur[idx] = run; run += cnt[idx]; }
  }
  if (t == 1023) ptr[n] = lds[1023];
}

// ---------------- Kernel D: scatter (R2 form — measured fastest) -----------
__global__ __launch_bounds__(256) void scatter_kernel(
  const int* __restrict__ rows, const int* __restrict__ cols,
  const float* __restrict__ nbv, const float* __restrict__ ccv,
  int* curR, int* curC,
  int* nbrT, float* w0T, float* w1T,
  int* nbrS, float* w0S, float* w1S, int E)
{
  int e = blockIdx.x*256 + threadIdx.x;
  if (e < E){
    int r = rows[e], c = cols[e];
    float a = nbv[e], b = ccv[e];
    int pT = atomicAdd(&curR[r], 1);
    nbrT[pT] = c; w0T[pT] = a; w1T[pT] = b;
    int pS = atomicAdd(&curC[c], 1);
    nbrS[pS] = r; w0S[pS] = a; w1S[pS] = b;
  }
}

// ---------------- Kernel D2: streaming repack CSR arrays -> 8B records -----
// rec = (bf16(w0) | bf16(w1)<<16) << 32 | nbr
__global__ __launch_bounds__(256) void repack_kernel(
  const int* __restrict__ nbrT, const float* __restrict__ w0T, const float* __restrict__ w1T,
  const int* __restrict__ nbrS, const float* __restrict__ w0S, const float* __restrict__ w1S,
  u64* __restrict__ recT, u64* __restrict__ recS, int E)
{
  int e = blockIdx.x*256 + threadIdx.x;
  if (e < E){
    recT[e] = (((u64)(f2bf(w0T[e]) | (f2bf(w1T[e]) << 16))) << 32) | (u32)nbrT[e];
    recS[e] = (((u64)(f2bf(w0S[e]) | (f2bf(w1S[e]) << 16))) << 32) | (u32)nbrS[e];
  }
}

// ---------------- Kernel E: channel-sliced aggregation, contiguous tables --
// grid.z = 8 phases: dir = z>>2, slice = z&3 (z slowest -> phases in order).
// Per phase the gather table slice is CONTIGUOUS 3.2MB -> L2-resident.
// Wave = 4 edge-groups x 16 channels; 1 wave per segment per phase.
// stats layout: [slice][seg][blk0..5][16ch] u16
__global__ __launch_bounds__(256) void agg_kernel(
  const int* __restrict__ ptrC, const int* __restrict__ ptrR,
  const u64* __restrict__ recS, const u64* __restrict__ recT,
  const u32* __restrict__ mS, const u32* __restrict__ mT,
  u16* __restrict__ statsS, u16* __restrict__ statsT, int ns, int nt)
{
  const int z = blockIdx.z;
  const int dir = z >> 2, slice = z & 3;
  const int nseg = dir ? nt : ns;
  const int ntab = dir ? ns : nt;      // node count of the gathered table
  const int* ptr = dir ? ptrR : ptrC;
  const u64* rec = dir ? recT : recS;
  const u32* mtab = (dir ? mS : mT) + (size_t)slice*ntab*16;
  u16* stats = dir ? statsT : statsS;

  const int wid = threadIdx.x >> 6, lane = threadIdx.x & 63;
  const int seg = blockIdx.x*4 + wid;
  if (seg >= nseg) return;
  const int beg = ptr[seg], end = ptr[seg+1];
  const int egrp = lane >> 4, ch = lane & 15;

  float s0=0.f, s1=0.f, s2=0.f;
  float mx0=-INFINITY, mx1=-INFINITY, mx2=-INFINITY;

  const int nit = (end - beg + 3) >> 2;
  int e = beg + egrp;
  int k = 0;
  // 2-wide software pipeline: two independent record+gather chains in flight
  for (; k + 2 <= nit; k += 2, e += 8){
    bool v0 = e < end, v1 = (e + 4) < end;
    u64 p0 = 0, p1 = 0;
    if (v0) p0 = rec[e];
    if (v1) p1 = rec[e + 4];
    u32 f0 = 0, f1 = 0;
    if (v0) f0 = mtab[(int)(u32)p0 * 16 + ch];
    if (v1) f1 = mtab[(int)(u32)p1 * 16 + ch];
    if (v0){
      u32 wp = (u32)(p0 >> 32);
      float a = bflo(wp), b = bfhi(wp);
      float g0 = bflo(f0) * a, g1 = bfhi(f0) * b, g2 = g1 * a;
      s0 += g0; s1 += g1; s2 += g2;
      mx0 = fmaxf(mx0, g0); mx1 = fmaxf(mx1, g1); mx2 = fmaxf(mx2, g2);
    }
    if (v1){
      u32 wp = (u32)(p1 >> 32);
      float a = bflo(wp), b = bfhi(wp);
      float g0 = bflo(f1) * a, g1 = bfhi(f1) * b, g2 = g1 * a;
      s0 += g0; s1 += g1; s2 += g2;
      mx0 = fmaxf(mx0, g0); mx1 = fmaxf(mx1, g1); mx2 = fmaxf(mx2, g2);
    }
  }
  for (; k < nit; k++, e += 4){
    if (e < end){
      u64 p = rec[e];
      u32 f = mtab[(int)(u32)p * 16 + ch];
      u32 wp = (u32)(p >> 32);
      float a = bflo(wp), b = bfhi(wp);
      float g0 = bflo(f) * a, g1 = bfhi(f) * b, g2 = g1 * a;
      s0 += g0; s1 += g1; s2 += g2;
      mx0 = fmaxf(mx0, g0); mx1 = fmaxf(mx1, g1); mx2 = fmaxf(mx2, g2);
    }
  }

  // reduce across the 4 edge-groups (lane bits 4,5)
  #pragma unroll
  for (int d = 16; d <= 32; d <<= 1){
    s0 += __shfl_xor(s0, d, 64);
    s1 += __shfl_xor(s1, d, 64);
    s2 += __shfl_xor(s2, d, 64);
    mx0 = fmaxf(mx0, __shfl_xor(mx0, d, 64));
    mx1 = fmaxf(mx1, __shfl_xor(mx1, d, 64));
    mx2 = fmaxf(mx2, __shfl_xor(mx2, d, 64));
  }
  if (end == beg){ mx0 = 0.f; mx1 = 0.f; mx2 = 0.f; }  // empty segment -> 0

  if (lane < 16){
    size_t base = ((size_t)slice*nseg + seg)*96 + ch;
    stats[base      ] = (u16)f2bf(s0);
    stats[base + 16 ] = (u16)f2bf(s1);
    stats[base + 32 ] = (u16)f2bf(s2);
    stats[base + 48 ] = (u16)f2bf(mx0);
    stats[base + 64 ] = (u16)f2bf(mx1);
    stats[base + 80 ] = (u16)f2bf(mx2);
  }
}

// ---------------- Kernel F: MFMA GEMM  [64 segs x 576] @ [576 x 64] --------
#define HROW 584   // padded LDS row stride in u16

__global__ __launch_bounds__(256) void lin_kernel(
  const u16* __restrict__ statsS, const u16* __restrict__ statsT,
  const int* __restrict__ ptrC, const int* __restrict__ ptrR,
  const u16* __restrict__ WtS, const u16* __restrict__ WtT,
  const float* __restrict__ srcB, const float* __restrict__ tgtB,
  float* __restrict__ outp, int ns, int nt)
{
  __shared__ u16 h[64*HROW];
  __shared__ float invc[64];
  const int dir = blockIdx.y;
  const u16* stats = dir ? statsT : statsS;
  const int* ptr   = dir ? ptrR : ptrC;
  const u16* Wt    = dir ? WtT : WtS;
  const float* Bg  = dir ? tgtB : srcB;
  const int n = dir ? nt : ns;
  float* out = outp + (dir ? (size_t)ns*64 : 0);
  const int tid = threadIdx.x;
  const int wv = tid >> 6, lane = tid & 63;
  const int seg0 = blockIdx.x * 64;
  if (seg0 >= n) return;

  const int bcol = wv*16 + (lane & 15);
  const int krow = (lane >> 4) * 8;
  short8 bfrag[18];
  #pragma unroll
  for (int t = 0; t < 18; t++)
    bfrag[t] = *(const short8*)&Wt[(size_t)bcol*576 + t*32 + krow];

  if (tid < 64){
    int seg = seg0 + tid;
    float c = (seg < n) ? (float)(ptr[seg+1] - ptr[seg]) : 1.f;
    invc[tid] = 1.f / fmaxf(c, 1.f);
  }
  __syncthreads();

  // stage stats -> h[seg][576] = [sum_p | sum_p/c | max_p] per branch p
  // stats layout: [slice][seg][blk][16] u16
  for (int idx = tid; idx < 64*192; idx += 256){
    int s = idx / 192, i = idx - s*192;
    int blk = i >> 5, cp = (i & 31) * 2;     // cp = even channel 0..62
    int seg = seg0 + s;
    u32 v = 0;
    if (seg < n)
      v = *(const u32*)&stats[((size_t)(cp >> 4)*n + seg)*96 + blk*16 + (cp & 15)];
    u32* hrow = (u32*)&h[s*HROW];
    if (blk < 3){
      hrow[(blk*192 + cp) >> 1] = v;
      float ic = invc[s];
      hrow[(blk*192 + 64 + cp) >> 1] = f2bf(bflo(v)*ic) | (f2bf(bfhi(v)*ic) << 16);
    } else {
      hrow[((blk-3)*192 + 128 + cp) >> 1] = v;
    }
  }
  __syncthreads();

  f32x4 acc[4] = {};
  const int arow = lane & 15;
  #pragma unroll
  for (int t = 0; t < 18; t++){
    #pragma unroll
    for (int rb = 0; rb < 4; rb++){
      short8 a = *(const short8*)&h[(rb*16 + arow)*HROW + t*32 + krow];
      acc[rb] = __builtin_amdgcn_mfma_f32_16x16x32_bf16(a, bfrag[t], acc[rb], 0, 0, 0);
    }
  }

  float bv = Bg[bcol] + Bg[64 + bcol] + Bg[128 + bcol];
  #pragma unroll
  for (int rb = 0; rb < 4; rb++){
    #pragma unroll
    for (int r = 0; r < 4; r++){
      int seg = seg0 + rb*16 + (lane >> 4)*4 + r;
      if (seg < n) out[(size_t)seg*64 + bcol] = acc[rb][r] + bv;
    }
  }
}

extern "C" void kernel_launch(void* const* d_in, const int* in_sizes, int n_in,
                              void* d_out, int out_size, void* d_ws, size_t ws_size,
                              hipStream_t stream)
{
  const float* xs   = (const float*)d_in[0];
  const float* xt   = (const float*)d_in[1];
  const int*   rows = (const int*)  d_in[2];
  const int*   cols = (const int*)  d_in[3];
  const float* nbv  = (const float*)d_in[4];
  const float* ccv  = (const float*)d_in[5];
  const float* w_s  = (const float*)d_in[6];
  const float* w_t  = (const float*)d_in[7];
  const float* w_sc = (const float*)d_in[8];
  const float* w_tc = (const float*)d_in[9];
  const float* srcW = (const float*)d_in[10];
  const float* srcB = (const float*)d_in[11];
  const float* tgtW = (const float*)d_in[12];
  const float* tgtB = (const float*)d_in[13];
  const int ns = in_sizes[0] / 64;
  const int nt = in_sizes[1] / 64;
  const int E  = in_sizes[4];

  char* ws = (char*)d_ws;
  size_t off = 0;
  auto alloc = [&](size_t bytes)->char* {
    char* p = ws + off;
    off = (off + bytes + 255) & ~(size_t)255;
    return p;
  };
  u32* mS    = (u32*)alloc((size_t)ns*64*4);
  u32* mT    = (u32*)alloc((size_t)nt*64*4);
  int* cntC  = (int*)alloc((size_t)(ns+nt)*4);
  int* cntR  = cntC + ns;
  int* ptrC  = (int*)alloc((size_t)(ns+1)*4);
  int* ptrR  = (int*)alloc((size_t)(nt+1)*4);
  int* curC  = (int*)alloc((size_t)ns*4);
  int* curR  = (int*)alloc((size_t)nt*4);
  int*   nbrS = (int*)  alloc((size_t)E*4);
  float* w0S  = (float*)alloc((size_t)E*4);
  float* w1S  = (float*)alloc((size_t)E*4);
  int*   nbrT = (int*)  alloc((size_t)E*4);
  float* w0T  = (float*)alloc((size_t)E*4);
  float* w1T  = (float*)alloc((size_t)E*4);
  u64* recS   = (u64*)alloc((size_t)E*8);
  u64* recT   = (u64*)alloc((size_t)E*8);
  u16* statsS = (u16*)alloc((size_t)ns*384*2);
  u16* statsT = (u16*)alloc((size_t)nt*384*2);
  u16* WtS    = (u16*)alloc((size_t)576*64*2);
  u16* WtT    = (u16*)alloc((size_t)576*64*2);

  hipMemsetAsync(cntC, 0, (size_t)(ns+nt)*4, stream);
  proj_kernel<<<dim3(128,2), 256, 0, stream>>>(xs,xt,w_s,w_t,w_sc,w_tc,mS,mT,ns,nt);
  wprep_kernel<<<(576*64 + 255)/256, 256, 0, stream>>>(srcW,tgtW,WtS,WtT);
  hist_kernel<<<(E+255)/256, 256, 0, stream>>>(rows,cols,cntR,cntC,E);
  scan_kernel<<<2, 1024, 0, stream>>>(cntC,cntR,ptrC,ptrR,curC,curR,ns,nt);
  scatter_kernel<<<(E+255)/256, 256, 0, stream>>>(rows,cols,nbv,ccv,curR,curC,
                                                  nbrT,w0T,w1T,nbrS,w0S,w1S,E);
  repack_kernel<<<(E+255)/256, 256, 0, stream>>>(nbrT,w0T,w1T,nbrS,w0S,w1S,
                                                 recT,recS,E);
  const int mseg = (ns > nt ? ns : nt);
  agg_kernel<<<dim3((mseg+3)/4, 1, 8), 256, 0, stream>>>(ptrC,ptrR,recS,recT,
                                                         mS,mT,statsS,statsT,ns,nt);
  lin_kernel<<<dim3((mseg+63)/64, 2), 256, 0, stream>>>(statsS,statsT,ptrC,ptrR,
                                                        WtS,WtT,srcB,tgtB,
                                                        (float*)d_out,ns,nt);
}

// Round 6
// 875.607 us; speedup vs baseline: 1.4491x; 1.1856x over previous
//
#include <hip/hip_runtime.h>
#include <hip/hip_bf16.h>

typedef unsigned int u32;
typedef unsigned short u16;
typedef unsigned long long u64;
typedef __attribute__((ext_vector_type(8))) short short8;
typedef __attribute__((ext_vector_type(4))) float f32x4;

__device__ __forceinline__ u32 f2bf(float f){
  u32 u = __float_as_uint(f);
  return (u + 0x7fffu + ((u >> 16) & 1u)) >> 16;   // RNE to bf16
}
__device__ __forceinline__ float bflo(u32 p){ return __uint_as_float(p << 16); }
__device__ __forceinline__ float bfhi(u32 p){ return __uint_as_float(p & 0xffff0000u); }

// ---------------- Kernel A: dense projections -> per-slice packed tables ---
// tab layout: [slice(4)][node][16ch] u32, each u32 = pack(primary, cci)
// slice table = n*64B contiguous  (3.2MB for n=50000 -> L2-resident)
__global__ __launch_bounds__(256) void proj_kernel(
    const float* __restrict__ xs, const float* __restrict__ xt,
    const float* __restrict__ w_s, const float* __restrict__ w_t,
    const float* __restrict__ w_s_cci, const float* __restrict__ w_t_cci,
    u32* __restrict__ mS, u32* __restrict__ mT, int ns, int nt)
{
  __shared__ float wa[4096], wb[4096];
  const int dir = blockIdx.y;
  const float* x  = dir ? xt : xs;
  const float* wA = dir ? w_t : w_s;
  const float* wB = dir ? w_t_cci : w_s_cci;
  u32* out = dir ? mT : mS;
  const int n = dir ? nt : ns;
  const int tid = threadIdx.x;
  for (int i = tid; i < 4096; i += 256){ wa[i] = wA[i]; wb[i] = wB[i]; }
  __syncthreads();
  const int wid = tid >> 6, lane = tid & 63;
  const int slice = lane >> 4, ch = lane & 15;
  for (int row = blockIdx.x*4 + wid; row < n; row += gridDim.x*4){
    float xv = x[(size_t)row*64 + lane];
    float accA = 0.f, accB = 0.f;
    #pragma unroll
    for (int k = 0; k < 64; k++){
      float xk = __shfl(xv, k, 64);
      accA = fmaf(xk, wa[k*64 + lane], accA);
      accB = fmaf(xk, wb[k*64 + lane], accB);
    }
    out[((size_t)slice*n + row)*16 + ch] = f2bf(accA) | (f2bf(accB) << 16);
  }
}

// ---------------- Kernel A2: transpose+cast linear weights -----------------
__global__ __launch_bounds__(256) void wprep_kernel(
  const float* __restrict__ srcW, const float* __restrict__ tgtW,
  u16* __restrict__ WtS, u16* __restrict__ WtT)
{
  int idx = blockIdx.x*256 + threadIdx.x;
  if (idx < 576*64){
    int col = idx / 576, k = idx - col*576;
    WtS[idx] = (u16)f2bf(srcW[(size_t)k*64 + col]);
    WtT[idx] = (u16)f2bf(tgtW[(size_t)k*64 + col]);
  }
}

// ---------------- Kernel B: histogram ----------------
__global__ __launch_bounds__(256) void hist_kernel(
  const int* __restrict__ rows, const int* __restrict__ cols,
  int* cntR, int* cntC, int E)
{
  int e = blockIdx.x*256 + threadIdx.x;
  if (e < E){
    atomicAdd(&cntR[rows[e]], 1);
    atomicAdd(&cntC[cols[e]], 1);
  }
}

// ---------------- Parallel scan (3 kernels) --------------------------------
// scan1: per-block (1024 elems) local exclusive scan + block totals
__global__ __launch_bounds__(256) void scan1_kernel(
  const int* __restrict__ cntC, const int* __restrict__ cntR,
  int* __restrict__ locC, int* __restrict__ locR,
  int* __restrict__ bsum, int ns, int nt)
{
  const int arr = blockIdx.y;
  const int* cnt = arr ? cntR : cntC;
  int* loc = arr ? locR : locC;
  const int n = arr ? nt : ns;
  const int base = blockIdx.x*1024 + threadIdx.x*4;
  int v[4]; int s = 0;
  #pragma unroll
  for (int i = 0; i < 4; i++){ int idx = base+i; v[i] = (idx < n) ? cnt[idx] : 0; s += v[i]; }
  const int lane = threadIdx.x & 63, wid = threadIdx.x >> 6;
  int ps = s;
  #pragma unroll
  for (int d = 1; d < 64; d <<= 1){ int t = __shfl_up(ps, d, 64); if (lane >= d) ps += t; }
  __shared__ int wsum[4];
  if (lane == 63) wsum[wid] = ps;
  __syncthreads();
  int woff = 0;
  for (int w = 0; w < wid; w++) woff += wsum[w];
  int ex = woff + ps - s;
  #pragma unroll
  for (int i = 0; i < 4; i++){ int idx = base+i; if (idx < n) loc[idx] = ex; ex += v[i]; }
  if (threadIdx.x == 255) bsum[arr*64 + blockIdx.x] = woff + ps;
}

// scan2: one block; wave w scans array w's block sums (<=64 blocks)
__global__ __launch_bounds__(128) void scan2_kernel(
  int* __restrict__ bsum, int* __restrict__ ptrC, int* __restrict__ ptrR,
  int ns, int nt)
{
  const int wid = threadIdx.x >> 6, lane = threadIdx.x & 63;
  const int n = wid ? nt : ns;
  const int nb = (n + 1023) >> 10;
  int v = (lane < nb) ? bsum[wid*64 + lane] : 0;
  int ps = v;
  #pragma unroll
  for (int d = 1; d < 64; d <<= 1){ int t = __shfl_up(ps, d, 64); if (lane >= d) ps += t; }
  if (lane < nb) bsum[wid*64 + lane] = ps - v;    // exclusive block offset
  if (lane == 63){ if (wid) ptrR[nt] = ps; else ptrC[ns] = ps; }
}

// scan3: add block offsets -> final ptr + cur
__global__ __launch_bounds__(256) void scan3_kernel(
  const int* __restrict__ locC, const int* __restrict__ locR,
  const int* __restrict__ bsum,
  int* __restrict__ ptrC, int* __restrict__ ptrR,
  int* __restrict__ curC, int* __restrict__ curR, int ns, int nt)
{
  const int arr = blockIdx.y;
  const int* loc = arr ? locR : locC;
  int* ptr = arr ? ptrR : ptrC;
  int* cur = arr ? curR : curC;
  const int n = arr ? nt : ns;
  const int off = bsum[arr*64 + blockIdx.x];
  const int base = blockIdx.x*1024 + threadIdx.x;
  #pragma unroll
  for (int i = 0; i < 4; i++){
    int idx = base + i*256;
    if (idx < n){ int p = loc[idx] + off; ptr[idx] = p; cur[idx] = p; }
  }
}

// ---------------- Kernel D: scatter (R2 form — measured fastest) -----------
__global__ __launch_bounds__(256) void scatter_kernel(
  const int* __restrict__ rows, const int* __restrict__ cols,
  const float* __restrict__ nbv, const float* __restrict__ ccv,
  int* curR, int* curC,
  int* nbrT, float* w0T, float* w1T,
  int* nbrS, float* w0S, float* w1S, int E)
{
  int e = blockIdx.x*256 + threadIdx.x;
  if (e < E){
    int r = rows[e], c = cols[e];
    float a = nbv[e], b = ccv[e];
    int pT = atomicAdd(&curR[r], 1);
    nbrT[pT] = c; w0T[pT] = a; w1T[pT] = b;
    int pS = atomicAdd(&curC[c], 1);
    nbrS[pS] = r; w0S[pS] = a; w1S[pS] = b;
  }
}

// ---------------- Kernel D2: repack -> 8B records --------------------------
// rec = nb(u16) | bf16(a)<<16 | bf16(b)<<32 | bf16(a*b)<<48   (requires n<65536)
__global__ __launch_bounds__(256) void repack_kernel(
  const int* __restrict__ nbrT, const float* __restrict__ w0T, const float* __restrict__ w1T,
  const int* __restrict__ nbrS, const float* __restrict__ w0S, const float* __restrict__ w1S,
  u64* __restrict__ recT, u64* __restrict__ recS, int E)
{
  int e = blockIdx.x*256 + threadIdx.x;
  if (e < E){
    {
      float a = w0T[e], b = w1T[e];
      recT[e] = (u64)(u16)nbrT[e] | ((u64)f2bf(a) << 16) | ((u64)f2bf(b) << 32)
              | ((u64)f2bf(a*b) << 48);
    }
    {
      float a = w0S[e], b = w1S[e];
      recS[e] = (u64)(u16)nbrS[e] | ((u64)f2bf(a) << 16) | ((u64)f2bf(b) << 32)
              | ((u64)f2bf(a*b) << 48);
    }
  }
}

// ---------------- Kernel E: channel-sliced aggregation v3 ------------------
// grid.z = 8 phases: dir = z>>2, slice = z&3. Slice table contiguous 3.2MB.
// Wave = 4 edge-groups x 16 channels. 3-batch pipeline, unpredicated quads.
__global__ __launch_bounds__(256) void agg_kernel(
  const int* __restrict__ ptrC, const int* __restrict__ ptrR,
  const u64* __restrict__ recS, const u64* __restrict__ recT,
  const u32* __restrict__ mS, const u32* __restrict__ mT,
  u16* __restrict__ statsS, u16* __restrict__ statsT, int ns, int nt)
{
  const int z = blockIdx.z;
  const int dir = z >> 2, slice = z & 3;
  const int nseg = dir ? nt : ns;
  const int ntab = dir ? ns : nt;
  const int* ptr = dir ? ptrR : ptrC;
  const u64* rec = dir ? recT : recS;
  const u32* mtab = (dir ? mS : mT) + (size_t)slice*ntab*16;
  u16* stats = dir ? statsT : statsS;

  const int wid = threadIdx.x >> 6, lane = threadIdx.x & 63;
  const int seg = blockIdx.x*4 + wid;
  if (seg >= nseg) return;
  const int beg = ptr[seg], end = ptr[seg+1];
  const u32 egrp = (u32)(lane >> 4);
  const u32 chb = (u32)((lane & 15) << 2);   // channel byte offset

  float s0=0.f, s1=0.f, s2=0.f;
  float mx0=-INFINITY, mx1=-INFINITY, mx2=-INFINITY;

  const int cnt = end - beg;
  const u32 nq = (u32)(cnt >> 2);
  const u32 r  = (u32)(cnt & 3);
  u32 e = (u32)beg + egrp;

  #define GREC(i)   (rec[(size_t)(u32)(i)])
  #define GFT(p)    (*(const u32*)((const char*)mtab + (size_t)(((u32)(p) & 0xffffu)*64u + chb)))
  #define CONSUME(p, f) { \
    u32 lo_ = (u32)(p), hi_ = (u32)((p) >> 32); \
    float a_ = bfhi(lo_), b_ = bflo(hi_), ab_ = bfhi(hi_); \
    float tl_ = bflo(f), th_ = bfhi(f); \
    float g0_ = tl_*a_, g1_ = th_*b_, g2_ = th_*ab_; \
    s0 += g0_; s1 += g1_; s2 += g2_; \
    mx0 = fmaxf(mx0, g0_); mx1 = fmaxf(mx1, g1_); mx2 = fmaxf(mx2, g2_); }

  u32 k = 0;
  if (nq >= 8){
    u64 p0 = GREC(e),    p1 = GREC(e+4),  p2 = GREC(e+8),  p3 = GREC(e+12);
    u32 f0 = GFT(p0),    f1 = GFT(p1),    f2 = GFT(p2),    f3 = GFT(p3);
    u64 q0 = GREC(e+16), q1 = GREC(e+20), q2 = GREC(e+24), q3 = GREC(e+28);
    for (; k + 12 <= nq; k += 4, e += 16){
      u64 r0 = GREC(e+32), r1 = GREC(e+36), r2 = GREC(e+40), r3 = GREC(e+44);
      u32 g0 = GFT(q0), g1 = GFT(q1), g2 = GFT(q2), g3 = GFT(q3);
      CONSUME(p0, f0); CONSUME(p1, f1); CONSUME(p2, f2); CONSUME(p3, f3);
      p0=q0; p1=q1; p2=q2; p3=q3;
      f0=g0; f1=g1; f2=g2; f3=g3;
      q0=r0; q1=r1; q2=r2; q3=r3;
    }
    u32 g0 = GFT(q0), g1 = GFT(q1), g2 = GFT(q2), g3 = GFT(q3);
    CONSUME(p0, f0); CONSUME(p1, f1); CONSUME(p2, f2); CONSUME(p3, f3);
    CONSUME(q0, g0); CONSUME(q1, g1); CONSUME(q2, g2); CONSUME(q3, g3);
    k += 8; e += 32;
  }
  for (; k < nq; k++, e += 4){
    u64 p = GREC(e);
    u32 f = GFT(p);
    CONSUME(p, f);
  }
  if (egrp < r){
    u64 p = GREC((u32)beg + 4*nq + egrp);
    u32 f = GFT(p);
    CONSUME(p, f);
  }
  #undef GREC
  #undef GFT
  #undef CONSUME

  // reduce across the 4 edge-groups (lane bits 4,5)
  #pragma unroll
  for (int d = 16; d <= 32; d <<= 1){
    s0 += __shfl_xor(s0, d, 64);
    s1 += __shfl_xor(s1, d, 64);
    s2 += __shfl_xor(s2, d, 64);
    mx0 = fmaxf(mx0, __shfl_xor(mx0, d, 64));
    mx1 = fmaxf(mx1, __shfl_xor(mx1, d, 64));
    mx2 = fmaxf(mx2, __shfl_xor(mx2, d, 64));
  }
  if (cnt == 0){ mx0 = 0.f; mx1 = 0.f; mx2 = 0.f; }  // empty segment -> 0

  if (lane < 16){
    size_t base = ((size_t)slice*nseg + seg)*96 + (lane & 15);
    stats[base      ] = (u16)f2bf(s0);
    stats[base + 16 ] = (u16)f2bf(s1);
    stats[base + 32 ] = (u16)f2bf(s2);
    stats[base + 48 ] = (u16)f2bf(mx0);
    stats[base + 64 ] = (u16)f2bf(mx1);
    stats[base + 80 ] = (u16)f2bf(mx2);
  }
}

// ---------------- Kernel F: MFMA GEMM  [64 segs x 576] @ [576 x 64] --------
#define HROW 584   // padded LDS row stride in u16

__global__ __launch_bounds__(256) void lin_kernel(
  const u16* __restrict__ statsS, const u16* __restrict__ statsT,
  const int* __restrict__ ptrC, const int* __restrict__ ptrR,
  const u16* __restrict__ WtS, const u16* __restrict__ WtT,
  const float* __restrict__ srcB, const float* __restrict__ tgtB,
  float* __restrict__ outp, int ns, int nt)
{
  __shared__ u16 h[64*HROW];
  __shared__ float invc[64];
  const int dir = blockIdx.y;
  const u16* stats = dir ? statsT : statsS;
  const int* ptr   = dir ? ptrR : ptrC;
  const u16* Wt    = dir ? WtT : WtS;
  const float* Bg  = dir ? tgtB : srcB;
  const int n = dir ? nt : ns;
  float* out = outp + (dir ? (size_t)ns*64 : 0);
  const int tid = threadIdx.x;
  const int wv = tid >> 6, lane = tid & 63;
  const int seg0 = blockIdx.x * 64;
  if (seg0 >= n) return;

  const int bcol = wv*16 + (lane & 15);
  const int krow = (lane >> 4) * 8;
  short8 bfrag[18];
  #pragma unroll
  for (int t = 0; t < 18; t++)
    bfrag[t] = *(const short8*)&Wt[(size_t)bcol*576 + t*32 + krow];

  if (tid < 64){
    int seg = seg0 + tid;
    float c = (seg < n) ? (float)(ptr[seg+1] - ptr[seg]) : 1.f;
    invc[tid] = 1.f / fmaxf(c, 1.f);
  }
  __syncthreads();

  // stage stats -> h[seg][576] = [sum_p | sum_p/c | max_p] per branch p
  // stats layout: [slice][seg][blk][16] u16
  for (int idx = tid; idx < 64*192; idx += 256){
    int s = idx / 192, i = idx - s*192;
    int blk = i >> 5, cp = (i & 31) * 2;     // cp = even channel 0..62
    int seg = seg0 + s;
    u32 v = 0;
    if (seg < n)
      v = *(const u32*)&stats[((size_t)(cp >> 4)*n + seg)*96 + blk*16 + (cp & 15)];
    u32* hrow = (u32*)&h[s*HROW];
    if (blk < 3){
      hrow[(blk*192 + cp) >> 1] = v;
      float ic = invc[s];
      hrow[(blk*192 + 64 + cp) >> 1] = f2bf(bflo(v)*ic) | (f2bf(bfhi(v)*ic) << 16);
    } else {
      hrow[((blk-3)*192 + 128 + cp) >> 1] = v;
    }
  }
  __syncthreads();

  f32x4 acc[4] = {};
  const int arow = lane & 15;
  #pragma unroll
  for (int t = 0; t < 18; t++){
    #pragma unroll
    for (int rb = 0; rb < 4; rb++){
      short8 a = *(const short8*)&h[(rb*16 + arow)*HROW + t*32 + krow];
      acc[rb] = __builtin_amdgcn_mfma_f32_16x16x32_bf16(a, bfrag[t], acc[rb], 0, 0, 0);
    }
  }

  float bv = Bg[bcol] + Bg[64 + bcol] + Bg[128 + bcol];
  #pragma unroll
  for (int rb = 0; rb < 4; rb++){
    #pragma unroll
    for (int r = 0; r < 4; r++){
      int seg = seg0 + rb*16 + (lane >> 4)*4 + r;
      if (seg < n) out[(size_t)seg*64 + bcol] = acc[rb][r] + bv;
    }
  }
}

extern "C" void kernel_launch(void* const* d_in, const int* in_sizes, int n_in,
                              void* d_out, int out_size, void* d_ws, size_t ws_size,
                              hipStream_t stream)
{
  const float* xs   = (const float*)d_in[0];
  const float* xt   = (const float*)d_in[1];
  const int*   rows = (const int*)  d_in[2];
  const int*   cols = (const int*)  d_in[3];
  const float* nbv  = (const float*)d_in[4];
  const float* ccv  = (const float*)d_in[5];
  const float* w_s  = (const float*)d_in[6];
  const float* w_t  = (const float*)d_in[7];
  const float* w_sc = (const float*)d_in[8];
  const float* w_tc = (const float*)d_in[9];
  const float* srcW = (const float*)d_in[10];
  const float* srcB = (const float*)d_in[11];
  const float* tgtW = (const float*)d_in[12];
  const float* tgtB = (const float*)d_in[13];
  const int ns = in_sizes[0] / 64;
  const int nt = in_sizes[1] / 64;
  const int E  = in_sizes[4];

  char* ws = (char*)d_ws;
  size_t off = 0;
  auto alloc = [&](size_t bytes)->char* {
    char* p = ws + off;
    off = (off + bytes + 255) & ~(size_t)255;
    return p;
  };
  u32* mS    = (u32*)alloc((size_t)ns*64*4);
  u32* mT    = (u32*)alloc((size_t)nt*64*4);
  int* cntC  = (int*)alloc((size_t)(ns+nt)*4);
  int* cntR  = cntC + ns;
  int* ptrC  = (int*)alloc((size_t)(ns+1)*4);
  int* ptrR  = (int*)alloc((size_t)(nt+1)*4);
  int* curC  = (int*)alloc((size_t)ns*4);
  int* curR  = (int*)alloc((size_t)nt*4);
  int* locC  = (int*)alloc((size_t)ns*4);
  int* locR  = (int*)alloc((size_t)nt*4);
  int* bsum  = (int*)alloc((size_t)128*4);
  int*   nbrS = (int*)  alloc((size_t)E*4);
  float* w0S  = (float*)alloc((size_t)E*4);
  float* w1S  = (float*)alloc((size_t)E*4);
  int*   nbrT = (int*)  alloc((size_t)E*4);
  float* w0T  = (float*)alloc((size_t)E*4);
  float* w1T  = (float*)alloc((size_t)E*4);
  u64* recS   = (u64*)alloc((size_t)E*8);
  u64* recT   = (u64*)alloc((size_t)E*8);
  u16* statsS = (u16*)alloc((size_t)ns*384*2);
  u16* statsT = (u16*)alloc((size_t)nt*384*2);
  u16* WtS    = (u16*)alloc((size_t)576*64*2);
  u16* WtT    = (u16*)alloc((size_t)576*64*2);

  const int mseg = (ns > nt ? ns : nt);
  const int nsb = (mseg + 1023) / 1024;   // scan blocks per array (<=64)

  hipMemsetAsync(cntC, 0, (size_t)(ns+nt)*4, stream);
  proj_kernel<<<dim3(128,2), 256, 0, stream>>>(xs,xt,w_s,w_t,w_sc,w_tc,mS,mT,ns,nt);
  wprep_kernel<<<(576*64 + 255)/256, 256, 0, stream>>>(srcW,tgtW,WtS,WtT);
  hist_kernel<<<(E+255)/256, 256, 0, stream>>>(rows,cols,cntR,cntC,E);
  scan1_kernel<<<dim3(nsb,2), 256, 0, stream>>>(cntC,cntR,locC,locR,bsum,ns,nt);
  scan2_kernel<<<1, 128, 0, stream>>>(bsum,ptrC,ptrR,ns,nt);
  scan3_kernel<<<dim3(nsb,2), 256, 0, stream>>>(locC,locR,bsum,ptrC,ptrR,curC,curR,ns,nt);
  scatter_kernel<<<(E+255)/256, 256, 0, stream>>>(rows,cols,nbv,ccv,curR,curC,
                                                  nbrT,w0T,w1T,nbrS,w0S,w1S,E);
  repack_kernel<<<(E+255)/256, 256, 0, stream>>>(nbrT,w0T,w1T,nbrS,w0S,w1S,
                                                 recT,recS,E);
  agg_kernel<<<dim3((mseg+3)/4, 1, 8), 256, 0, stream>>>(ptrC,ptrR,recS,recT,
                                                         mS,mT,statsS,statsT,ns,nt);
  lin_kernel<<<dim3((mseg+63)/64, 2), 256, 0, stream>>>(statsS,statsT,ptrC,ptrR,
                                                        WtS,WtT,srcB,tgtB,
                                                        (float*)d_out,ns,nt);
}

// Round 7
// 845.943 us; speedup vs baseline: 1.4999x; 1.0351x over previous
//
#include <hip/hip_runtime.h>
#include <hip/hip_bf16.h>

typedef unsigned int u32;
typedef unsigned short u16;
typedef unsigned long long u64;
typedef __attribute__((ext_vector_type(8))) short short8;
typedef __attribute__((ext_vector_type(4))) float f32x4;

__device__ __forceinline__ u32 f2bf(float f){
  u32 u = __float_as_uint(f);
  return (u + 0x7fffu + ((u >> 16) & 1u)) >> 16;   // RNE to bf16
}
__device__ __forceinline__ float bflo(u32 p){ return __uint_as_float(p << 16); }
__device__ __forceinline__ float bfhi(u32 p){ return __uint_as_float(p & 0xffff0000u); }

// ---------------- Kernel A: dense projections -> per-slice packed tables ---
// tab layout: [slice(4)][node][16ch] u32, u32 = pack(primary, cci)
// slice table = n*64B contiguous (3.2MB for n=50000 -> L2-resident per XCD)
__global__ __launch_bounds__(256) void proj_kernel(
    const float* __restrict__ xs, const float* __restrict__ xt,
    const float* __restrict__ w_s, const float* __restrict__ w_t,
    const float* __restrict__ w_s_cci, const float* __restrict__ w_t_cci,
    u32* __restrict__ mS, u32* __restrict__ mT, int ns, int nt)
{
  __shared__ float wa[4096], wb[4096];
  const int dir = blockIdx.y;
  const float* x  = dir ? xt : xs;
  const float* wA = dir ? w_t : w_s;
  const float* wB = dir ? w_t_cci : w_s_cci;
  u32* out = dir ? mT : mS;
  const int n = dir ? nt : ns;
  const int tid = threadIdx.x;
  for (int i = tid; i < 4096; i += 256){ wa[i] = wA[i]; wb[i] = wB[i]; }
  __syncthreads();
  const int wid = tid >> 6, lane = tid & 63;
  const int slice = lane >> 4, ch = lane & 15;
  for (int row = blockIdx.x*4 + wid; row < n; row += gridDim.x*4){
    float xv = x[(size_t)row*64 + lane];
    float accA = 0.f, accB = 0.f;
    #pragma unroll
    for (int k = 0; k < 64; k++){
      float xk = __shfl(xv, k, 64);
      accA = fmaf(xk, wa[k*64 + lane], accA);
      accB = fmaf(xk, wb[k*64 + lane], accB);
    }
    out[((size_t)slice*n + row)*16 + ch] = f2bf(accA) | (f2bf(accB) << 16);
  }
}

// ---------------- Kernel B: histogram (+ fused weight transpose) -----------
__global__ __launch_bounds__(256) void hist_kernel(
  const int* __restrict__ rows, const int* __restrict__ cols,
  int* cntR, int* cntC, int E,
  const float* __restrict__ srcW, const float* __restrict__ tgtW,
  u16* __restrict__ WtS, u16* __restrict__ WtT)
{
  int e = blockIdx.x*256 + threadIdx.x;
  if (e < E){
    atomicAdd(&cntR[rows[e]], 1);
    atomicAdd(&cntC[cols[e]], 1);
  }
  if (e < 576*64){
    int col = e / 576, k = e - col*576;
    WtS[e] = (u16)f2bf(srcW[(size_t)k*64 + col]);
    WtT[e] = (u16)f2bf(tgtW[(size_t)k*64 + col]);
  }
}

// ---------------- Kernel C: single-pass decoupled-lookback scan ------------
// state[arr*64+b]: bits 63..62 = flag (0 invalid, 1 aggregate, 2 inclusive),
// low 32 = value. Zeroed by the launch memset. 98 blocks, all co-resident.
__global__ __launch_bounds__(256) void scan_kernel(
  const int* __restrict__ cntC, const int* __restrict__ cntR,
  int* __restrict__ ptrC, int* __restrict__ ptrR,
  int* __restrict__ curC, int* __restrict__ curR,
  u64* __restrict__ state, int ns, int nt)
{
  const int arr = blockIdx.y;
  const int* cnt = arr ? cntR : cntC;
  int* ptr = arr ? ptrR : ptrC;
  int* cur = arr ? curR : curC;
  const int n = arr ? nt : ns;
  const int nb = (n + 1023) >> 10;
  const int b = blockIdx.x;
  if (b >= nb) return;
  u64* st = state + arr*64;

  const int base = b*1024 + threadIdx.x*4;
  int v[4]; int s = 0;
  #pragma unroll
  for (int i = 0; i < 4; i++){ int idx = base+i; v[i] = (idx < n) ? cnt[idx] : 0; s += v[i]; }
  const int lane = threadIdx.x & 63, wid = threadIdx.x >> 6;
  int ps = s;
  #pragma unroll
  for (int d = 1; d < 64; d <<= 1){ int t = __shfl_up(ps, d, 64); if (lane >= d) ps += t; }
  __shared__ int wsum[4];
  __shared__ int bloff;
  if (lane == 63) wsum[wid] = ps;
  __syncthreads();
  int woff = 0;
  for (int w = 0; w < wid; w++) woff += wsum[w];
  if (threadIdx.x == 0){
    int btot = wsum[0] + wsum[1] + wsum[2] + wsum[3];
    u64 flag1 = (b == 0) ? (2ull << 62) : (1ull << 62);
    __hip_atomic_store(&st[b], flag1 | (u64)(u32)btot,
                       __ATOMIC_RELEASE, __HIP_MEMORY_SCOPE_AGENT);
    int run = 0;
    if (b > 0){
      int i = b - 1;
      while (1){
        u64 p = __hip_atomic_load(&st[i], __ATOMIC_ACQUIRE, __HIP_MEMORY_SCOPE_AGENT);
        u64 fl = p >> 62;
        if (fl == 0){ __builtin_amdgcn_s_sleep(1); continue; }
        run += (int)(u32)p;
        if (fl == 2) break;
        i--;
      }
      __hip_atomic_store(&st[b], (2ull << 62) | (u64)(u32)(run + btot),
                         __ATOMIC_RELEASE, __HIP_MEMORY_SCOPE_AGENT);
    }
    bloff = run;
    if (b == nb - 1) ptr[n] = run + btot;
  }
  __syncthreads();
  int ex = bloff + woff + ps - s;
  #pragma unroll
  for (int i = 0; i < 4; i++){
    int idx = base+i;
    if (idx < n){ ptr[idx] = ex; cur[idx] = ex; }
    ex += v[i];
  }
}

// ---------------- Kernel D: scatter, 2 edges/thread (12 store streams) -----
__global__ __launch_bounds__(256) void scatter_kernel(
  const int* __restrict__ rows, const int* __restrict__ cols,
  const float* __restrict__ nbv, const float* __restrict__ ccv,
  int* curR, int* curC,
  int* nbrT, float* w0T, float* w1T,
  int* nbrS, float* w0S, float* w1S, int E)
{
  int e = (blockIdx.x*256 + threadIdx.x)*2;
  if (e + 1 < E){
    int r0 = rows[e], r1 = rows[e+1], c0 = cols[e], c1 = cols[e+1];
    float a0 = nbv[e], a1 = nbv[e+1], b0 = ccv[e], b1 = ccv[e+1];
    int pT0 = atomicAdd(&curR[r0], 1);
    int pT1 = atomicAdd(&curR[r1], 1);
    nbrT[pT0] = c0; w0T[pT0] = a0; w1T[pT0] = b0;
    nbrT[pT1] = c1; w0T[pT1] = a1; w1T[pT1] = b1;
    int pS0 = atomicAdd(&curC[c0], 1);
    int pS1 = atomicAdd(&curC[c1], 1);
    nbrS[pS0] = r0; w0S[pS0] = a0; w1S[pS0] = b0;
    nbrS[pS1] = r1; w0S[pS1] = a1; w1S[pS1] = b1;
  } else if (e < E){
    int r = rows[e], c = cols[e];
    float a = nbv[e], b = ccv[e];
    int pT = atomicAdd(&curR[r], 1);
    nbrT[pT] = c; w0T[pT] = a; w1T[pT] = b;
    int pS = atomicAdd(&curC[c], 1);
    nbrS[pS] = r; w0S[pS] = a; w1S[pS] = b;
  }
}

// ---------------- Kernel D2: repack -> 8B records --------------------------
// rec = nb(u16) | bf16(a)<<16 | bf16(b)<<32 | bf16(a*b)<<48   (needs n<65536)
__global__ __launch_bounds__(256) void repack_kernel(
  const int* __restrict__ nbrT, const float* __restrict__ w0T, const float* __restrict__ w1T,
  const int* __restrict__ nbrS, const float* __restrict__ w0S, const float* __restrict__ w1S,
  u64* __restrict__ recT, u64* __restrict__ recS, int E)
{
  int e = blockIdx.x*256 + threadIdx.x;
  if (e < E){
    {
      float a = w0T[e], b = w1T[e];
      recT[e] = (u64)(u16)nbrT[e] | ((u64)f2bf(a) << 16) | ((u64)f2bf(b) << 32)
              | ((u64)f2bf(a*b) << 48);
    }
    {
      float a = w0S[e], b = w1S[e];
      recS[e] = (u64)(u16)nbrS[e] | ((u64)f2bf(a) << 16) | ((u64)f2bf(b) << 32)
              | ((u64)f2bf(a*b) << 48);
    }
  }
}

// ---------------- Kernel E: channel-sliced aggregation v4 (per-dir) --------
// grid: ((nseg+3)/4, 1, 4);  blockIdx.z = slice. Slice table contiguous 3.2MB.
// Wave = 4 edge-groups x 16 channels, one segment per wave.
// Flat batch-8 loads: 8 recs -> 8 gathers -> 8 consumes (compiler-proof MLP).
__global__ __launch_bounds__(256) void agg_kernel(
  const int* __restrict__ ptr, const u64* __restrict__ rec,
  const u32* __restrict__ mtabFull, u16* __restrict__ stats,
  int nseg, int ntab)
{
  const int slice = blockIdx.z;
  const u32* mtab = mtabFull + (size_t)slice*ntab*16;

  const int wid = threadIdx.x >> 6, lane = threadIdx.x & 63;
  const int seg = blockIdx.x*4 + wid;
  if (seg >= nseg) return;
  const int beg = ptr[seg], end = ptr[seg+1];
  const u32 egrp = (u32)(lane >> 4);
  const char* mt = (const char*)mtab + ((lane & 15) << 2);

  float s0=0.f, s1=0.f, s2=0.f;
  float mx0=-INFINITY, mx1=-INFINITY, mx2=-INFINITY;

  const int cnt = end - beg;
  const u32 nq = (u32)(cnt >> 2);
  const u32 r  = (u32)(cnt & 3);
  u32 e = (u32)beg + egrp;

  #define GREC(i)   (rec[(size_t)(u32)(i)])
  #define GFT(p)    (*(const u32*)(mt + (size_t)((((u32)(p) & 0xffffu) << 6))))
  #define CONSUME(p, f) { \
    u32 lo_ = (u32)(p), hi_ = (u32)((p) >> 32); \
    float a_ = bfhi(lo_), b_ = bflo(hi_), ab_ = bfhi(hi_); \
    float tl_ = bflo(f), th_ = bfhi(f); \
    float g0_ = tl_*a_, g1_ = th_*b_, g2_ = th_*ab_; \
    s0 += g0_; s1 += g1_; s2 += g2_; \
    mx0 = fmaxf(mx0, g0_); mx1 = fmaxf(mx1, g1_); mx2 = fmaxf(mx2, g2_); }

  u32 k = 0;
  for (; k + 8 <= nq; k += 8, e += 32){
    u64 p0 = GREC(e),    p1 = GREC(e+4),  p2 = GREC(e+8),  p3 = GREC(e+12);
    u64 p4 = GREC(e+16), p5 = GREC(e+20), p6 = GREC(e+24), p7 = GREC(e+28);
    u32 f0 = GFT(p0), f1 = GFT(p1), f2 = GFT(p2), f3 = GFT(p3);
    u32 f4 = GFT(p4), f5 = GFT(p5), f6 = GFT(p6), f7 = GFT(p7);
    CONSUME(p0, f0); CONSUME(p1, f1); CONSUME(p2, f2); CONSUME(p3, f3);
    CONSUME(p4, f4); CONSUME(p5, f5); CONSUME(p6, f6); CONSUME(p7, f7);
  }
  for (; k + 2 <= nq; k += 2, e += 8){
    u64 p0 = GREC(e), p1 = GREC(e+4);
    u32 f0 = GFT(p0), f1 = GFT(p1);
    CONSUME(p0, f0); CONSUME(p1, f1);
  }
  if (k < nq){
    u64 p = GREC(e);
    u32 f = GFT(p);
    CONSUME(p, f);
  }
  if (egrp < r){
    u64 p = GREC((u32)beg + 4*nq + egrp);
    u32 f = GFT(p);
    CONSUME(p, f);
  }
  #undef GREC
  #undef GFT
  #undef CONSUME

  // reduce across the 4 edge-groups (lane bits 4,5)
  #pragma unroll
  for (int d = 16; d <= 32; d <<= 1){
    s0 += __shfl_xor(s0, d, 64);
    s1 += __shfl_xor(s1, d, 64);
    s2 += __shfl_xor(s2, d, 64);
    mx0 = fmaxf(mx0, __shfl_xor(mx0, d, 64));
    mx1 = fmaxf(mx1, __shfl_xor(mx1, d, 64));
    mx2 = fmaxf(mx2, __shfl_xor(mx2, d, 64));
  }
  if (cnt == 0){ mx0 = 0.f; mx1 = 0.f; mx2 = 0.f; }  // empty segment -> 0

  if (lane < 16){
    size_t base = ((size_t)slice*nseg + seg)*96 + (lane & 15);
    stats[base      ] = (u16)f2bf(s0);
    stats[base + 16 ] = (u16)f2bf(s1);
    stats[base + 32 ] = (u16)f2bf(s2);
    stats[base + 48 ] = (u16)f2bf(mx0);
    stats[base + 64 ] = (u16)f2bf(mx1);
    stats[base + 80 ] = (u16)f2bf(mx2);
  }
}

// ---------------- Kernel F: MFMA GEMM  [64 segs x 576] @ [576 x 64] --------
#define HROW 584   // padded LDS row stride in u16

__global__ __launch_bounds__(256) void lin_kernel(
  const u16* __restrict__ statsS, const u16* __restrict__ statsT,
  const int* __restrict__ ptrC, const int* __restrict__ ptrR,
  const u16* __restrict__ WtS, const u16* __restrict__ WtT,
  const float* __restrict__ srcB, const float* __restrict__ tgtB,
  float* __restrict__ outp, int ns, int nt)
{
  __shared__ u16 h[64*HROW];
  __shared__ float invc[64];
  const int dir = blockIdx.y;
  const u16* stats = dir ? statsT : statsS;
  const int* ptr   = dir ? ptrR : ptrC;
  const u16* Wt    = dir ? WtT : WtS;
  const float* Bg  = dir ? tgtB : srcB;
  const int n = dir ? nt : ns;
  float* out = outp + (dir ? (size_t)ns*64 : 0);
  const int tid = threadIdx.x;
  const int wv = tid >> 6, lane = tid & 63;
  const int seg0 = blockIdx.x * 64;
  if (seg0 >= n) return;

  const int bcol = wv*16 + (lane & 15);
  const int krow = (lane >> 4) * 8;
  short8 bfrag[18];
  #pragma unroll
  for (int t = 0; t < 18; t++)
    bfrag[t] = *(const short8*)&Wt[(size_t)bcol*576 + t*32 + krow];

  if (tid < 64){
    int seg = seg0 + tid;
    float c = (seg < n) ? (float)(ptr[seg+1] - ptr[seg]) : 1.f;
    invc[tid] = 1.f / fmaxf(c, 1.f);
  }
  __syncthreads();

  // stage stats -> h[seg][576] = [sum_p | sum_p/c | max_p] per branch p
  // stats layout: [slice][seg][blk][16] u16
  for (int idx = tid; idx < 64*192; idx += 256){
    int s = idx / 192, i = idx - s*192;
    int blk = i >> 5, cp = (i & 31) * 2;     // cp = even channel 0..62
    int seg = seg0 + s;
    u32 v = 0;
    if (seg < n)
      v = *(const u32*)&stats[((size_t)(cp >> 4)*n + seg)*96 + blk*16 + (cp & 15)];
    u32* hrow = (u32*)&h[s*HROW];
    if (blk < 3){
      hrow[(blk*192 + cp) >> 1] = v;
      float ic = invc[s];
      hrow[(blk*192 + 64 + cp) >> 1] = f2bf(bflo(v)*ic) | (f2bf(bfhi(v)*ic) << 16);
    } else {
      hrow[((blk-3)*192 + 128 + cp) >> 1] = v;
    }
  }
  __syncthreads();

  f32x4 acc[4] = {};
  const int arow = lane & 15;
  #pragma unroll
  for (int t = 0; t < 18; t++){
    #pragma unroll
    for (int rb = 0; rb < 4; rb++){
      short8 a = *(const short8*)&h[(rb*16 + arow)*HROW + t*32 + krow];
      acc[rb] = __builtin_amdgcn_mfma_f32_16x16x32_bf16(a, bfrag[t], acc[rb], 0, 0, 0);
    }
  }

  float bv = Bg[bcol] + Bg[64 + bcol] + Bg[128 + bcol];
  #pragma unroll
  for (int rb = 0; rb < 4; rb++){
    #pragma unroll
    for (int r = 0; r < 4; r++){
      int seg = seg0 + rb*16 + (lane >> 4)*4 + r;
      if (seg < n) out[(size_t)seg*64 + bcol] = acc[rb][r] + bv;
    }
  }
}

extern "C" void kernel_launch(void* const* d_in, const int* in_sizes, int n_in,
                              void* d_out, int out_size, void* d_ws, size_t ws_size,
                              hipStream_t stream)
{
  const float* xs   = (const float*)d_in[0];
  const float* xt   = (const float*)d_in[1];
  const int*   rows = (const int*)  d_in[2];
  const int*   cols = (const int*)  d_in[3];
  const float* nbv  = (const float*)d_in[4];
  const float* ccv  = (const float*)d_in[5];
  const float* w_s  = (const float*)d_in[6];
  const float* w_t  = (const float*)d_in[7];
  const float* w_sc = (const float*)d_in[8];
  const float* w_tc = (const float*)d_in[9];
  const float* srcW = (const float*)d_in[10];
  const float* srcB = (const float*)d_in[11];
  const float* tgtW = (const float*)d_in[12];
  const float* tgtB = (const float*)d_in[13];
  const int ns = in_sizes[0] / 64;
  const int nt = in_sizes[1] / 64;
  const int E  = in_sizes[4];

  char* ws = (char*)d_ws;
  size_t off = 0;
  auto alloc = [&](size_t bytes)->char* {
    char* p = ws + off;
    off = (off + bytes + 255) & ~(size_t)255;
    return p;
  };
  u32* mS    = (u32*)alloc((size_t)ns*64*4);
  u32* mT    = (u32*)alloc((size_t)nt*64*4);
  // cnt + lookback state in ONE chunk so a single memset zeroes both
  char* zblk = alloc((size_t)(ns+nt)*4 + 1024);
  int* cntC  = (int*)zblk;
  int* cntR  = cntC + ns;
  u64* state = (u64*)(cntC + ns + nt);
  int* ptrC  = (int*)alloc((size_t)(ns+1)*4);
  int* ptrR  = (int*)alloc((size_t)(nt+1)*4);
  int* curC  = (int*)alloc((size_t)ns*4);
  int* curR  = (int*)alloc((size_t)nt*4);
  int*   nbrS = (int*)  alloc((size_t)E*4);
  float* w0S  = (float*)alloc((size_t)E*4);
  float* w1S  = (float*)alloc((size_t)E*4);
  int*   nbrT = (int*)  alloc((size_t)E*4);
  float* w0T  = (float*)alloc((size_t)E*4);
  float* w1T  = (float*)alloc((size_t)E*4);
  u64* recS   = (u64*)alloc((size_t)E*8);
  u64* recT   = (u64*)alloc((size_t)E*8);
  u16* statsS = (u16*)alloc((size_t)ns*384*2);
  u16* statsT = (u16*)alloc((size_t)nt*384*2);
  u16* WtS    = (u16*)alloc((size_t)576*64*2);
  u16* WtT    = (u16*)alloc((size_t)576*64*2);

  const int mseg = (ns > nt ? ns : nt);
  const int nsb = (mseg + 1023) / 1024;   // scan blocks per array (<=64)

  hipMemsetAsync(zblk, 0, (size_t)(ns+nt)*4 + 1024, stream);
  proj_kernel<<<dim3(128,2), 256, 0, stream>>>(xs,xt,w_s,w_t,w_sc,w_tc,mS,mT,ns,nt);
  hist_kernel<<<(E+255)/256, 256, 0, stream>>>(rows,cols,cntR,cntC,E,
                                               srcW,tgtW,WtS,WtT);
  scan_kernel<<<dim3(nsb,2), 256, 0, stream>>>(cntC,cntR,ptrC,ptrR,curC,curR,
                                               state,ns,nt);
  scatter_kernel<<<(E/2+255)/256, 256, 0, stream>>>(rows,cols,nbv,ccv,curR,curC,
                                                    nbrT,w0T,w1T,nbrS,w0S,w1S,E);
  repack_kernel<<<(E+255)/256, 256, 0, stream>>>(nbrT,w0T,w1T,nbrS,w0S,w1S,
                                                 recT,recS,E);
  // dir 0: segments = source cells, gathers TARGET features
  agg_kernel<<<dim3((ns+3)/4, 1, 4), 256, 0, stream>>>(ptrC,recS,mT,statsS,ns,nt);
  // dir 1: segments = target cells, gathers SOURCE features
  agg_kernel<<<dim3((nt+3)/4, 1, 4), 256, 0, stream>>>(ptrR,recT,mS,statsT,nt,ns);
  lin_kernel<<<dim3((mseg+63)/64, 2), 256, 0, stream>>>(statsS,statsT,ptrC,ptrR,
                                                        WtS,WtT,srcB,tgtB,
                                                        (float*)d_out,ns,nt);
}

// Round 8
// 803.040 us; speedup vs baseline: 1.5801x; 1.0534x over previous
//
#include <hip/hip_runtime.h>
#include <hip/hip_bf16.h>

typedef unsigned int u32;
typedef unsigned short u16;
typedef unsigned long long u64;
typedef __attribute__((ext_vector_type(8))) short short8;
typedef __attribute__((ext_vector_type(4))) float f32x4;

#define BSHIFT 7          // 128 segments per bucket
#define NBUCK  512        // covers up to 65536 segments

__device__ __forceinline__ u32 f2bf(float f){
  u32 u = __float_as_uint(f);
  return (u + 0x7fffu + ((u >> 16) & 1u)) >> 16;   // RNE to bf16
}
__device__ __forceinline__ float bflo(u32 p){ return __uint_as_float(p << 16); }
__device__ __forceinline__ float bfhi(u32 p){ return __uint_as_float(p & 0xffff0000u); }

// ---------------- Kernel A: dense projections -> per-slice packed tables ---
// tab layout: [slice(4)][node][16ch] u32, u32 = pack(primary, cci)
__global__ __launch_bounds__(256) void proj_kernel(
    const float* __restrict__ xs, const float* __restrict__ xt,
    const float* __restrict__ w_s, const float* __restrict__ w_t,
    const float* __restrict__ w_s_cci, const float* __restrict__ w_t_cci,
    u32* __restrict__ mS, u32* __restrict__ mT, int ns, int nt)
{
  __shared__ float wa[4096], wb[4096];
  const int dir = blockIdx.y;
  const float* x  = dir ? xt : xs;
  const float* wA = dir ? w_t : w_s;
  const float* wB = dir ? w_t_cci : w_s_cci;
  u32* out = dir ? mT : mS;
  const int n = dir ? nt : ns;
  const int tid = threadIdx.x;
  for (int i = tid; i < 4096; i += 256){ wa[i] = wA[i]; wb[i] = wB[i]; }
  __syncthreads();
  const int wid = tid >> 6, lane = tid & 63;
  const int slice = lane >> 4, ch = lane & 15;
  for (int row = blockIdx.x*4 + wid; row < n; row += gridDim.x*4){
    float xv = x[(size_t)row*64 + lane];
    float accA = 0.f, accB = 0.f;
    #pragma unroll
    for (int k = 0; k < 64; k++){
      float xk = __shfl(xv, k, 64);
      accA = fmaf(xk, wa[k*64 + lane], accA);
      accB = fmaf(xk, wb[k*64 + lane], accB);
    }
    out[((size_t)slice*n + row)*16 + ch] = f2bf(accA) | (f2bf(accB) << 16);
  }
}

// ---------------- Kernel B: histogram (+ fused weight transpose) -----------
__global__ __launch_bounds__(256) void hist_kernel(
  const int* __restrict__ rows, const int* __restrict__ cols,
  int* cntR, int* cntC, int E,
  const float* __restrict__ srcW, const float* __restrict__ tgtW,
  u16* __restrict__ WtS, u16* __restrict__ WtT)
{
  int e = blockIdx.x*256 + threadIdx.x;
  if (e < E){
    atomicAdd(&cntR[rows[e]], 1);
    atomicAdd(&cntC[cols[e]], 1);
  }
  if (e < 576*64){
    int col = e / 576, k = e - col*576;
    WtS[e] = (u16)f2bf(srcW[(size_t)k*64 + col]);
    WtT[e] = (u16)f2bf(tgtW[(size_t)k*64 + col]);
  }
}

// ---------------- Kernel C: single-pass decoupled-lookback scan ------------
__global__ __launch_bounds__(256) void scan_kernel(
  const int* __restrict__ cntC, const int* __restrict__ cntR,
  int* __restrict__ ptrC, int* __restrict__ ptrR,
  int* __restrict__ curC, int* __restrict__ curR,
  u64* __restrict__ state, int ns, int nt)
{
  const int arr = blockIdx.y;
  const int* cnt = arr ? cntR : cntC;
  int* ptr = arr ? ptrR : ptrC;
  int* cur = arr ? curR : curC;
  const int n = arr ? nt : ns;
  const int nb = (n + 1023) >> 10;
  const int b = blockIdx.x;
  if (b >= nb) return;
  u64* st = state + arr*64;

  const int base = b*1024 + threadIdx.x*4;
  int v[4]; int s = 0;
  #pragma unroll
  for (int i = 0; i < 4; i++){ int idx = base+i; v[i] = (idx < n) ? cnt[idx] : 0; s += v[i]; }
  const int lane = threadIdx.x & 63, wid = threadIdx.x >> 6;
  int ps = s;
  #pragma unroll
  for (int d = 1; d < 64; d <<= 1){ int t = __shfl_up(ps, d, 64); if (lane >= d) ps += t; }
  __shared__ int wsum[4];
  __shared__ int bloff;
  if (lane == 63) wsum[wid] = ps;
  __syncthreads();
  int woff = 0;
  for (int w = 0; w < wid; w++) woff += wsum[w];
  if (threadIdx.x == 0){
    int btot = wsum[0] + wsum[1] + wsum[2] + wsum[3];
    u64 flag1 = (b == 0) ? (2ull << 62) : (1ull << 62);
    __hip_atomic_store(&st[b], flag1 | (u64)(u32)btot,
                       __ATOMIC_RELEASE, __HIP_MEMORY_SCOPE_AGENT);
    int run = 0;
    if (b > 0){
      int i = b - 1;
      while (1){
        u64 p = __hip_atomic_load(&st[i], __ATOMIC_ACQUIRE, __HIP_MEMORY_SCOPE_AGENT);
        u64 fl = p >> 62;
        if (fl == 0){ __builtin_amdgcn_s_sleep(1); continue; }
        run += (int)(u32)p;
        if (fl == 2) break;
        i--;
      }
      __hip_atomic_store(&st[b], (2ull << 62) | (u64)(u32)(run + btot),
                         __ATOMIC_RELEASE, __HIP_MEMORY_SCOPE_AGENT);
    }
    bloff = run;
    if (b == nb - 1) ptr[n] = run + btot;
  }
  __syncthreads();
  int ex = bloff + woff + ps - s;
  #pragma unroll
  for (int i = 0; i < 4; i++){
    int idx = base+i;
    if (idx < n){ ptr[idx] = ex; cur[idx] = ex; }
    ex += v[i];
  }
}

// ---------------- Kernel C2: bucket cursor init ----------------------------
// gcur[b] = ptr[min(b*128, n)]   (bucket region start in final CSR order)
__global__ __launch_bounds__(512) void binit_kernel(
  const int* __restrict__ ptrC, const int* __restrict__ ptrR,
  u32* __restrict__ gcurS, u32* __restrict__ gcurT, int ns, int nt)
{
  const int b = threadIdx.x;
  if (blockIdx.x == 0){
    int idx = b << BSHIFT; if (idx > ns) idx = ns;
    gcurS[b] = (u32)ptrC[idx];
  } else {
    int idx = b << BSHIFT; if (idx > nt) idx = nt;
    gcurT[b] = (u32)ptrR[idx];
  }
}

// ---------------- Kernel D: pass-1 bucketed partition ----------------------
// tmp rec = seg(u16) | nb(u16)<<16 | bf16(a)<<32 | bf16(b)<<48
// Block-privatized: LDS hist -> chunk reservation -> dense bucket stores.
__global__ __launch_bounds__(256) void part_kernel(
  const int* __restrict__ rows, const int* __restrict__ cols,
  const float* __restrict__ nbv, const float* __restrict__ ccv,
  u32* __restrict__ gcurT, u32* __restrict__ gcurS,
  u64* __restrict__ tmpT, u64* __restrict__ tmpS, int E)
{
  __shared__ u32 histT[NBUCK], histS[NBUCK];
  const int tid = threadIdx.x;
  const int e0 = blockIdx.x * 2048;
  for (int i = tid; i < NBUCK; i += 256){ histT[i] = 0; histS[i] = 0; }
  __syncthreads();

  int r[8], c[8]; float a[8], b[8];
  #pragma unroll
  for (int i = 0; i < 8; i++){
    int e = e0 + i*256 + tid;
    if (e < E){
      r[i] = rows[e]; c[i] = cols[e]; a[i] = nbv[e]; b[i] = ccv[e];
      atomicAdd(&histT[r[i] >> BSHIFT], 1);
      atomicAdd(&histS[c[i] >> BSHIFT], 1);
    } else r[i] = -1;
  }
  __syncthreads();
  for (int i = tid; i < NBUCK; i += 256){
    u32 cT = histT[i]; histT[i] = cT ? atomicAdd(&gcurT[i], cT) : 0;
    u32 cS = histS[i]; histS[i] = cS ? atomicAdd(&gcurS[i], cS) : 0;
  }
  __syncthreads();
  #pragma unroll
  for (int i = 0; i < 8; i++){
    if (r[i] >= 0){
      u32 fa = f2bf(a[i]), fb = f2bf(b[i]);
      u64 w = ((u64)fa << 32) | ((u64)fb << 48);
      u32 pT = atomicAdd(&histT[r[i] >> BSHIFT], 1);
      tmpT[pT] = w | (u32)r[i] | ((u32)c[i] << 16);
      u32 pS = atomicAdd(&histS[c[i] >> BSHIFT], 1);
      tmpS[pS] = w | (u32)c[i] | ((u32)r[i] << 16);
    }
  }
}

// ---------------- Kernel D2: pass-2 place into exact CSR slots -------------
// out rec = nb(u16) | bf16(a)<<16 | bf16(b)<<32 | bf16(a*b)<<48
__global__ __launch_bounds__(256) void place_kernel(
  const u64* __restrict__ tmpS, const u64* __restrict__ tmpT,
  int* __restrict__ curC, int* __restrict__ curR,
  u64* __restrict__ recS, u64* __restrict__ recT, int E)
{
  const int dir = blockIdx.y;
  const u64* tmp = dir ? tmpT : tmpS;
  int* cur = dir ? curR : curC;
  u64* rec = dir ? recT : recS;
  const int base = blockIdx.x*1024 + threadIdx.x;
  #pragma unroll
  for (int i = 0; i < 4; i++){
    int e = base + i*256;
    if (e < E){
      u64 t = tmp[e];
      u32 lo = (u32)t;
      int seg = (int)(lo & 0xffffu);
      u32 fa = (u32)(t >> 32) & 0xffffu, fb = (u32)(t >> 48);
      float fab = __uint_as_float(fa << 16) * __uint_as_float(fb << 16);
      int p = atomicAdd(&cur[seg], 1);
      rec[p] = (u64)(lo >> 16) | ((u64)fa << 16) | ((u64)fb << 32)
             | ((u64)f2bf(fab) << 48);
    }
  }
}

// ---------------- Kernel E: channel-sliced aggregation v4 (per-dir) --------
__global__ __launch_bounds__(256) void agg_kernel(
  const int* __restrict__ ptr, const u64* __restrict__ rec,
  const u32* __restrict__ mtabFull, u16* __restrict__ stats,
  int nseg, int ntab)
{
  const int slice = blockIdx.z;
  const u32* mtab = mtabFull + (size_t)slice*ntab*16;

  const int wid = threadIdx.x >> 6, lane = threadIdx.x & 63;
  const int seg = blockIdx.x*4 + wid;
  if (seg >= nseg) return;
  const int beg = ptr[seg], end = ptr[seg+1];
  const u32 egrp = (u32)(lane >> 4);
  const char* mt = (const char*)mtab + ((lane & 15) << 2);

  float s0=0.f, s1=0.f, s2=0.f;
  float mx0=-INFINITY, mx1=-INFINITY, mx2=-INFINITY;

  const int cnt = end - beg;
  const u32 nq = (u32)(cnt >> 2);
  const u32 r  = (u32)(cnt & 3);
  u32 e = (u32)beg + egrp;

  #define GREC(i)   (rec[(size_t)(u32)(i)])
  #define GFT(p)    (*(const u32*)(mt + (size_t)((((u32)(p) & 0xffffu) << 6))))
  #define CONSUME(p, f) { \
    u32 lo_ = (u32)(p), hi_ = (u32)((p) >> 32); \
    float a_ = bfhi(lo_), b_ = bflo(hi_), ab_ = bfhi(hi_); \
    float tl_ = bflo(f), th_ = bfhi(f); \
    float g0_ = tl_*a_, g1_ = th_*b_, g2_ = th_*ab_; \
    s0 += g0_; s1 += g1_; s2 += g2_; \
    mx0 = fmaxf(mx0, g0_); mx1 = fmaxf(mx1, g1_); mx2 = fmaxf(mx2, g2_); }

  u32 k = 0;
  for (; k + 8 <= nq; k += 8, e += 32){
    u64 p0 = GREC(e),    p1 = GREC(e+4),  p2 = GREC(e+8),  p3 = GREC(e+12);
    u64 p4 = GREC(e+16), p5 = GREC(e+20), p6 = GREC(e+24), p7 = GREC(e+28);
    u32 f0 = GFT(p0), f1 = GFT(p1), f2 = GFT(p2), f3 = GFT(p3);
    u32 f4 = GFT(p4), f5 = GFT(p5), f6 = GFT(p6), f7 = GFT(p7);
    CONSUME(p0, f0); CONSUME(p1, f1); CONSUME(p2, f2); CONSUME(p3, f3);
    CONSUME(p4, f4); CONSUME(p5, f5); CONSUME(p6, f6); CONSUME(p7, f7);
  }
  for (; k + 2 <= nq; k += 2, e += 8){
    u64 p0 = GREC(e), p1 = GREC(e+4);
    u32 f0 = GFT(p0), f1 = GFT(p1);
    CONSUME(p0, f0); CONSUME(p1, f1);
  }
  if (k < nq){
    u64 p = GREC(e);
    u32 f = GFT(p);
    CONSUME(p, f);
  }
  if (egrp < r){
    u64 p = GREC((u32)beg + 4*nq + egrp);
    u32 f = GFT(p);
    CONSUME(p, f);
  }
  #undef GREC
  #undef GFT
  #undef CONSUME

  #pragma unroll
  for (int d = 16; d <= 32; d <<= 1){
    s0 += __shfl_xor(s0, d, 64);
    s1 += __shfl_xor(s1, d, 64);
    s2 += __shfl_xor(s2, d, 64);
    mx0 = fmaxf(mx0, __shfl_xor(mx0, d, 64));
    mx1 = fmaxf(mx1, __shfl_xor(mx1, d, 64));
    mx2 = fmaxf(mx2, __shfl_xor(mx2, d, 64));
  }
  if (cnt == 0){ mx0 = 0.f; mx1 = 0.f; mx2 = 0.f; }

  if (lane < 16){
    size_t base = ((size_t)slice*nseg + seg)*96 + (lane & 15);
    stats[base      ] = (u16)f2bf(s0);
    stats[base + 16 ] = (u16)f2bf(s1);
    stats[base + 32 ] = (u16)f2bf(s2);
    stats[base + 48 ] = (u16)f2bf(mx0);
    stats[base + 64 ] = (u16)f2bf(mx1);
    stats[base + 80 ] = (u16)f2bf(mx2);
  }
}

// ---------------- Kernel F: MFMA GEMM  [64 segs x 576] @ [576 x 64] --------
#define HROW 584   // padded LDS row stride in u16

__global__ __launch_bounds__(256) void lin_kernel(
  const u16* __restrict__ statsS, const u16* __restrict__ statsT,
  const int* __restrict__ ptrC, const int* __restrict__ ptrR,
  const u16* __restrict__ WtS, const u16* __restrict__ WtT,
  const float* __restrict__ srcB, const float* __restrict__ tgtB,
  float* __restrict__ outp, int ns, int nt)
{
  __shared__ u16 h[64*HROW];
  __shared__ float invc[64];
  const int dir = blockIdx.y;
  const u16* stats = dir ? statsT : statsS;
  const int* ptr   = dir ? ptrR : ptrC;
  const u16* Wt    = dir ? WtT : WtS;
  const float* Bg  = dir ? tgtB : srcB;
  const int n = dir ? nt : ns;
  float* out = outp + (dir ? (size_t)ns*64 : 0);
  const int tid = threadIdx.x;
  const int wv = tid >> 6, lane = tid & 63;
  const int seg0 = blockIdx.x * 64;
  if (seg0 >= n) return;

  const int bcol = wv*16 + (lane & 15);
  const int krow = (lane >> 4) * 8;
  short8 bfrag[18];
  #pragma unroll
  for (int t = 0; t < 18; t++)
    bfrag[t] = *(const short8*)&Wt[(size_t)bcol*576 + t*32 + krow];

  if (tid < 64){
    int seg = seg0 + tid;
    float c = (seg < n) ? (float)(ptr[seg+1] - ptr[seg]) : 1.f;
    invc[tid] = 1.f / fmaxf(c, 1.f);
  }
  __syncthreads();

  for (int idx = tid; idx < 64*192; idx += 256){
    int s = idx / 192, i = idx - s*192;
    int blk = i >> 5, cp = (i & 31) * 2;
    int seg = seg0 + s;
    u32 v = 0;
    if (seg < n)
      v = *(const u32*)&stats[((size_t)(cp >> 4)*n + seg)*96 + blk*16 + (cp & 15)];
    u32* hrow = (u32*)&h[s*HROW];
    if (blk < 3){
      hrow[(blk*192 + cp) >> 1] = v;
      float ic = invc[s];
      hrow[(blk*192 + 64 + cp) >> 1] = f2bf(bflo(v)*ic) | (f2bf(bfhi(v)*ic) << 16);
    } else {
      hrow[((blk-3)*192 + 128 + cp) >> 1] = v;
    }
  }
  __syncthreads();

  f32x4 acc[4] = {};
  const int arow = lane & 15;
  #pragma unroll
  for (int t = 0; t < 18; t++){
    #pragma unroll
    for (int rb = 0; rb < 4; rb++){
      short8 a = *(const short8*)&h[(rb*16 + arow)*HROW + t*32 + krow];
      acc[rb] = __builtin_amdgcn_mfma_f32_16x16x32_bf16(a, bfrag[t], acc[rb], 0, 0, 0);
    }
  }

  float bv = Bg[bcol] + Bg[64 + bcol] + Bg[128 + bcol];
  #pragma unroll
  for (int rb = 0; rb < 4; rb++){
    #pragma unroll
    for (int r = 0; r < 4; r++){
      int seg = seg0 + rb*16 + (lane >> 4)*4 + r;
      if (seg < n) out[(size_t)seg*64 + bcol] = acc[rb][r] + bv;
    }
  }
}

extern "C" void kernel_launch(void* const* d_in, const int* in_sizes, int n_in,
                              void* d_out, int out_size, void* d_ws, size_t ws_size,
                              hipStream_t stream)
{
  const float* xs   = (const float*)d_in[0];
  const float* xt   = (const float*)d_in[1];
  const int*   rows = (const int*)  d_in[2];
  const int*   cols = (const int*)  d_in[3];
  const float* nbv  = (const float*)d_in[4];
  const float* ccv  = (const float*)d_in[5];
  const float* w_s  = (const float*)d_in[6];
  const float* w_t  = (const float*)d_in[7];
  const float* w_sc = (const float*)d_in[8];
  const float* w_tc = (const float*)d_in[9];
  const float* srcW = (const float*)d_in[10];
  const float* srcB = (const float*)d_in[11];
  const float* tgtW = (const float*)d_in[12];
  const float* tgtB = (const float*)d_in[13];
  const int ns = in_sizes[0] / 64;
  const int nt = in_sizes[1] / 64;
  const int E  = in_sizes[4];

  char* ws = (char*)d_ws;
  size_t off = 0;
  auto alloc = [&](size_t bytes)->char* {
    char* p = ws + off;
    off = (off + bytes + 255) & ~(size_t)255;
    return p;
  };
  u32* mS    = (u32*)alloc((size_t)ns*64*4);
  u32* mT    = (u32*)alloc((size_t)nt*64*4);
  char* zblk = alloc((size_t)(ns+nt)*4 + 1024);
  int* cntC  = (int*)zblk;
  int* cntR  = cntC + ns;
  u64* state = (u64*)(cntC + ns + nt);
  int* ptrC  = (int*)alloc((size_t)(ns+1)*4);
  int* ptrR  = (int*)alloc((size_t)(nt+1)*4);
  int* curC  = (int*)alloc((size_t)ns*4);
  int* curR  = (int*)alloc((size_t)nt*4);
  u32* gcurS = (u32*)alloc((size_t)NBUCK*4);
  u32* gcurT = (u32*)alloc((size_t)NBUCK*4);
  u64* tmpS  = (u64*)alloc((size_t)E*8);
  u64* tmpT  = (u64*)alloc((size_t)E*8);
  u64* recS  = (u64*)alloc((size_t)E*8);
  u64* recT  = (u64*)alloc((size_t)E*8);
  u16* statsS = (u16*)alloc((size_t)ns*384*2);
  u16* statsT = (u16*)alloc((size_t)nt*384*2);
  u16* WtS    = (u16*)alloc((size_t)576*64*2);
  u16* WtT    = (u16*)alloc((size_t)576*64*2);

  const int mseg = (ns > nt ? ns : nt);
  const int nsb = (mseg + 1023) / 1024;   // scan blocks per array (<=64)

  hipMemsetAsync(zblk, 0, (size_t)(ns+nt)*4 + 1024, stream);
  proj_kernel<<<dim3(128,2), 256, 0, stream>>>(xs,xt,w_s,w_t,w_sc,w_tc,mS,mT,ns,nt);
  hist_kernel<<<(E+255)/256, 256, 0, stream>>>(rows,cols,cntR,cntC,E,
                                               srcW,tgtW,WtS,WtT);
  scan_kernel<<<dim3(nsb,2), 256, 0, stream>>>(cntC,cntR,ptrC,ptrR,curC,curR,
                                               state,ns,nt);
  binit_kernel<<<2, NBUCK, 0, stream>>>(ptrC,ptrR,gcurS,gcurT,ns,nt);
  part_kernel<<<(E+2047)/2048, 256, 0, stream>>>(rows,cols,nbv,ccv,
                                                 gcurT,gcurS,tmpT,tmpS,E);
  place_kernel<<<dim3((E+1023)/1024, 2), 256, 0, stream>>>(tmpS,tmpT,curC,curR,
                                                           recS,recT,E);
  // dir 0: segments = source cells, gathers TARGET features
  agg_kernel<<<dim3((ns+3)/4, 1, 4), 256, 0, stream>>>(ptrC,recS,mT,statsS,ns,nt);
  // dir 1: segments = target cells, gathers SOURCE features
  agg_kernel<<<dim3((nt+3)/4, 1, 4), 256, 0, stream>>>(ptrR,recT,mS,statsT,nt,ns);
  lin_kernel<<<dim3((mseg+63)/64, 2), 256, 0, stream>>>(statsS,statsT,ptrC,ptrR,
                                                        WtS,WtT,srcB,tgtB,
                                                        (float*)d_out,ns,nt);
}